// Round 15
// baseline (800.328 us; speedup 1.0000x reference)
//
#include <hip/hip_runtime.h>

typedef __bf16 bf16;
typedef __bf16 bf16x8 __attribute__((ext_vector_type(8)));
typedef __bf16 bf16x4 __attribute__((ext_vector_type(4)));
typedef float f32x4 __attribute__((ext_vector_type(4)));

#define DEV __device__ __forceinline__

constexpr int B_ = 2, S_ = 2048, E_ = 2048, H_ = 16, KVH_ = 4, HD_ = 128, I_ = 8192;
constexpr int KVROW = 2 * KVH_ * HD_;   // 1024
constexpr int QKS = 3072;               // fused qkv row stride
constexpr float EPS_ = 1e-6f;
constexpr float SCALE_ = 0.08838834764831845f;  // 128^-0.5

DEV void gload_lds16(const bf16* g, bf16* l) {
  __builtin_amdgcn_global_load_lds(
      (const __attribute__((address_space(1))) void*)g,
      (__attribute__((address_space(3))) void*)l, 16, 0, 0);
}

// ---------------- fused f32 -> bf16 conversion of all 6 weights ----------------
__global__ __launch_bounds__(256) void cvt6_k(const float* __restrict__ s0, const float* __restrict__ s1,
                                              const float* __restrict__ s2, const float* __restrict__ s3,
                                              const float* __restrict__ s4, const float* __restrict__ s5,
                                              bf16* __restrict__ dst) {
  constexpr size_t N0 = 4194304, N1 = 2097152, N2 = 4194304,
                   N3 = 16777216, N4 = 16777216, N5 = 16777216;
  constexpr size_t TOT = N0 + N1 + N2 + N3 + N4 + N5;
  for (size_t i = ((size_t)blockIdx.x * 256 + threadIdx.x) * 8; i < TOT;
       i += (size_t)gridDim.x * 256 * 8) {
    size_t off = i; const float* sp;
    if (off < N0) sp = s0;
    else if ((off -= N0) < N1) sp = s1;
    else if ((off -= N1) < N2) sp = s2;
    else if ((off -= N2) < N3) sp = s3;
    else if ((off -= N3) < N4) sp = s4;
    else { off -= N4; sp = s5; }
    const float4* p = (const float4*)(sp + off);
    float4 a = p[0], b = p[1];
    bf16x8 o;
    o[0]=(bf16)a.x; o[1]=(bf16)a.y; o[2]=(bf16)a.z; o[3]=(bf16)a.w;
    o[4]=(bf16)b.x; o[5]=(bf16)b.y; o[6]=(bf16)b.z; o[7]=(bf16)b.w;
    *(bf16x8*)(dst + i) = o;
  }
}

// ---------------- RMSNorm: one block per row of E_=2048 -> bf16 out ----------------
template <typename InT>
__global__ __launch_bounds__(256) void rmsnorm_k(const InT* __restrict__ x,
                                                 const float* __restrict__ w,
                                                 bf16* __restrict__ y) {
  const int row = blockIdx.x, t = threadIdx.x;
  const size_t base = (size_t)row * E_ + t * 8;
  float v[8];
  if constexpr (sizeof(InT) == 2) {
    bf16x8 d = *(const bf16x8*)(x + base);
#pragma unroll
    for (int j = 0; j < 8; ++j) v[j] = (float)d[j];
  } else {
    const float4* p = (const float4*)(x + base);
    float4 a = p[0], b2 = p[1];
    v[0]=a.x; v[1]=a.y; v[2]=a.z; v[3]=a.w; v[4]=b2.x; v[5]=b2.y; v[6]=b2.z; v[7]=b2.w;
  }
  float ss = 0.f;
#pragma unroll
  for (int j = 0; j < 8; ++j) ss += v[j] * v[j];
#pragma unroll
  for (int off = 32; off; off >>= 1) ss += __shfl_xor(ss, off);
  __shared__ float red[4];
  if ((t & 63) == 0) red[t >> 6] = ss;
  __syncthreads();
  ss = red[0] + red[1] + red[2] + red[3];
  const float sc = rsqrtf(ss * (1.0f / E_) + EPS_);
  const float4* wp = (const float4*)(w + t * 8);
  float4 wa = wp[0], wb = wp[1];
  float wv[8] = {wa.x, wa.y, wa.z, wa.w, wb.x, wb.y, wb.z, wb.w};
  bf16x8 o;
#pragma unroll
  for (int j = 0; j < 8; ++j) o[j] = (bf16)(v[j] * sc * wv[j]);
  *(bf16x8*)(y + base) = o;
}

// ---------------- RoPE in place on fused qkv buffer [M][3072] ----------------
__global__ __launch_bounds__(256) void rope_k(bf16* __restrict__ qkvb) {
  const int gid = blockIdx.x * 256 + threadIdx.x;   // B*S*(H+KV)*64 total
  const int d = gid & 63;
  const int r = gid >> 6;
  const int hh = r % (H_ + KVH_);
  const int s = (r / (H_ + KVH_)) % S_;
  const int b = r / ((H_ + KVH_) * S_);
  bf16* p = qkvb + (size_t)(b * S_ + s) * QKS +
            (hh < H_ ? hh * HD_ : 2048 + (hh - H_) * HD_);
  const float invf = exp2f(-(float)d * (13.287712379549449f / 64.f)); // 10000^(-d/64)
  float sn, cs;
  sincosf((float)s * invf, &sn, &cs);
  const float x1 = (float)p[d], x2 = (float)p[d + 64];
  p[d] = (bf16)(x1 * cs - x2 * sn);
  p[d + 64] = (bf16)(x2 * cs + x1 * sn);
}

// ---------------- V transpose: qkvb[..][2560+kvh*128+d] -> vT[b][kvh][d][s] ----------------
__global__ __launch_bounds__(256) void vtrans_k(const bf16* __restrict__ qkvb,
                                                bf16* __restrict__ vT) {
  __shared__ bf16 lds[64 * 136];
  const int t = threadIdx.x;
  const int s0 = blockIdx.x * 64, kvh = blockIdx.y, b = blockIdx.z;
#pragma unroll
  for (int i = 0; i < 4; ++i) {   // stage 64 s-rows x 128 d, coalesced
    const int c = t + i * 256;
    const int row = c >> 4, slot = c & 15;
    *(bf16x8*)&lds[row * 136 + slot * 8] =
        *(const bf16x8*)(qkvb + (size_t)(b * S_ + s0 + row) * QKS + 2560 + kvh * HD_ + slot * 8);
  }
  __syncthreads();
#pragma unroll
  for (int i = 0; i < 4; ++i) {   // write 128 d-rows x 64 s, coalesced
    const int c = t + i * 256;
    const int d = c >> 3, ss = c & 7;
    bf16x8 pk;
#pragma unroll
    for (int j = 0; j < 8; ++j) pk[j] = lds[(ss * 8 + j) * 136 + d];
    *(bf16x8*)(vT + (size_t)((b * KVH_ + kvh) * HD_ + d) * S_ + s0 + ss * 8) = pk;
  }
}

// ---------------- Fused gate+up GEMM (r11 proven): h = silu(A@Wg^T)*(A@Wu^T) --------
__global__ __launch_bounds__(256, 2) void gemm_gu(const bf16* __restrict__ A,
                                                  const bf16* __restrict__ Wg,
                                                  const bf16* __restrict__ Wu,
                                                  bf16* __restrict__ out,
                                                  int M, int N, int K) {
  constexpr int BK = 64;
  __shared__ bf16 As[128 * BK];
  __shared__ bf16 Bg[128 * BK];
  __shared__ bf16 Bu[128 * BK];
  const int t = threadIdx.x, lane = t & 63, w = t >> 6;
  const int g = lane >> 4, l15 = lane & 15;
  const int bm = blockIdx.y, bn = blockIdx.x;   // r11 orientation (measured best)
  const int wm = w >> 1, wn = w & 1;
  f32x4 ag[4][4], au[4][4];
#pragma unroll
  for (int i = 0; i < 4; ++i)
#pragma unroll
    for (int j = 0; j < 4; ++j) { ag[i][j] = {0.f,0.f,0.f,0.f}; au[i][j] = {0.f,0.f,0.f,0.f}; }

  const bf16* Ab  = A  + (size_t)bm * 128 * K;
  const bf16* Wgb = Wg + (size_t)bn * 128 * K;
  const bf16* Wub = Wu + (size_t)bn * 128 * K;

  for (int k0 = 0; k0 < K; k0 += BK) {
    __syncthreads();
#pragma unroll
    for (int i = 0; i < 4; ++i) {
      const int c = t + i * 256;
      const int row = c >> 3, slot = c & 7;
      const size_t goff = (size_t)row * K + k0 + ((slot ^ (row & 7)) << 3);
      gload_lds16(Ab + goff, &As[c * 8]);
      gload_lds16(Wgb + goff, &Bg[c * 8]);
      gload_lds16(Wub + goff, &Bu[c * 8]);
    }
    __syncthreads();
#pragma unroll
    for (int ks = 0; ks < 2; ++ks) {
      bf16x8 af[4], bgv[4], buv[4];
#pragma unroll
      for (int mt = 0; mt < 4; ++mt) {
        const int row = wm * 64 + mt * 16 + l15;
        af[mt] = *(const bf16x8*)&As[row * BK + (((ks * 4 + g) ^ (row & 7)) << 3)];
      }
#pragma unroll
      for (int nt = 0; nt < 4; ++nt) {
        const int row = wn * 64 + nt * 16 + l15;
        const int off = row * BK + (((ks * 4 + g) ^ (row & 7)) << 3);
        bgv[nt] = *(const bf16x8*)&Bg[off];
        buv[nt] = *(const bf16x8*)&Bu[off];
      }
#pragma unroll
      for (int mt = 0; mt < 4; ++mt)
#pragma unroll
        for (int nt = 0; nt < 4; ++nt) {
          ag[mt][nt] = __builtin_amdgcn_mfma_f32_16x16x32_bf16(af[mt], bgv[nt], ag[mt][nt], 0, 0, 0);
          au[mt][nt] = __builtin_amdgcn_mfma_f32_16x16x32_bf16(af[mt], buv[nt], au[mt][nt], 0, 0, 0);
        }
    }
  }

  const int row0 = bm * 128 + wm * 64;
  const int col0 = bn * 128 + wn * 64;
#pragma unroll
  for (int nt = 0; nt < 4; ++nt) {
    const int col = col0 + nt * 16 + l15;
#pragma unroll
    for (int mt = 0; mt < 4; ++mt) {
#pragma unroll
      for (int r = 0; r < 4; ++r) {
        const int rowi = row0 + mt * 16 + g * 4 + r;
        const float gv = ag[mt][nt][r];
        const float hv = (gv / (1.f + __expf(-gv))) * au[mt][nt][r];
        out[(size_t)rowi * N + col] = (bf16)hv;
      }
    }
  }
}

// ---------------- gu-profile single-B GEMM: 128M x 256N tile, 256 thr / 4 waves ------
// Each wave: 64M x 128N out (acc[4][8]), 64 MFMA per K-step, 3 staged tiles (48 KiB).
// EPI: 0 = +bias -> bf16; 1 = + f32 ext -> bf16; 3 = + bf16 ext -> f32 (final)
template <int EPI, bool BIAS>
__global__ __launch_bounds__(256, 2) void gemm_n2(const bf16* __restrict__ A,
                                                  const bf16* __restrict__ W,
                                                  const float* __restrict__ bias0,
                                                  const float* __restrict__ bias1,
                                                  const void* __restrict__ ext,
                                                  void* __restrict__ out,
                                                  int M, int N, int K) {
  constexpr int BK = 64;
  __shared__ bf16 As[128 * BK];
  __shared__ bf16 Bs[256 * BK];
  const int t = threadIdx.x, lane = t & 63, w = t >> 6;
  const int g = lane >> 4, l15 = lane & 15;
  const int bm = blockIdx.y, bn = blockIdx.x;
  const int wm = w >> 1, wn = w & 1;
  f32x4 acc[4][8];
#pragma unroll
  for (int i = 0; i < 4; ++i)
#pragma unroll
    for (int j = 0; j < 8; ++j) acc[i][j] = {0.f, 0.f, 0.f, 0.f};

  const bf16* Ab = A + (size_t)bm * 128 * K;
  const bf16* Wb = W + (size_t)bn * 256 * K;

  for (int k0 = 0; k0 < K; k0 += BK) {
    __syncthreads();
#pragma unroll
    for (int i = 0; i < 4; ++i) {           // A: 128 rows
      const int c = t + i * 256;
      const int row = c >> 3, slot = c & 7;
      gload_lds16(Ab + (size_t)row * K + k0 + ((slot ^ (row & 7)) << 3), &As[c * 8]);
    }
#pragma unroll
    for (int i = 0; i < 8; ++i) {           // B: 256 rows
      const int c = t + i * 256;
      const int row = c >> 3, slot = c & 7;
      gload_lds16(Wb + (size_t)row * K + k0 + ((slot ^ (row & 7)) << 3), &Bs[c * 8]);
    }
    __syncthreads();
#pragma unroll
    for (int ks = 0; ks < 2; ++ks) {
      bf16x8 af[4], bfv[8];
#pragma unroll
      for (int mt = 0; mt < 4; ++mt) {
        const int row = wm * 64 + mt * 16 + l15;
        af[mt] = *(const bf16x8*)&As[row * BK + (((ks * 4 + g) ^ (row & 7)) << 3)];
      }
#pragma unroll
      for (int nt = 0; nt < 8; ++nt) {
        const int row = wn * 128 + nt * 16 + l15;
        bfv[nt] = *(const bf16x8*)&Bs[row * BK + (((ks * 4 + g) ^ (row & 7)) << 3)];
      }
#pragma unroll
      for (int mt = 0; mt < 4; ++mt)
#pragma unroll
        for (int nt = 0; nt < 8; ++nt)
          acc[mt][nt] = __builtin_amdgcn_mfma_f32_16x16x32_bf16(af[mt], bfv[nt], acc[mt][nt], 0, 0, 0);
    }
  }

  const int row0 = bm * 128 + wm * 64;
  const int col0 = bn * 256 + wn * 128;
#pragma unroll
  for (int nt = 0; nt < 8; ++nt) {
    const int col = col0 + nt * 16 + l15;
    float bv = 0.f;
    if constexpr (BIAS) bv = (col < 2048) ? bias0[col] : bias1[col - 2048];
#pragma unroll
    for (int mt = 0; mt < 4; ++mt) {
#pragma unroll
      for (int r = 0; r < 4; ++r) {
        const int rowi = row0 + mt * 16 + g * 4 + r;
        const size_t idx = (size_t)rowi * N + col;
        float v = acc[mt][nt][r] + bv;
        if constexpr (EPI == 0) {
          ((bf16*)out)[idx] = (bf16)v;
        } else if constexpr (EPI == 1) {
          v += ((const float*)ext)[idx];
          ((bf16*)out)[idx] = (bf16)v;
        } else {
          v += (float)((const bf16*)ext)[idx];
          ((float*)out)[idx] = v;
        }
      }
    }
  }
}

// ---------------- GEMM 128x128 (tier-B fallback, f32-weight staging) ----------
template <int EPI>
__global__ __launch_bounds__(256, 2) void gemm_bt(const bf16* __restrict__ A,
                                                  const float* __restrict__ Wp,
                                                  const float* __restrict__ bias,
                                                  const void* __restrict__ ext,
                                                  void* __restrict__ out,
                                                  int M, int N, int K) {
  constexpr int BK = 64;
  __shared__ bf16 As[128 * BK];
  __shared__ bf16 Bs[128 * BK];
  const int t = threadIdx.x, lane = t & 63, w = t >> 6;
  const int g = lane >> 4, l15 = lane & 15;
  const int bm = blockIdx.y, bn = blockIdx.x;
  const int wm = w >> 1, wn = w & 1;
  f32x4 acc[4][4];
#pragma unroll
  for (int i = 0; i < 4; ++i)
#pragma unroll
    for (int j = 0; j < 4; ++j) acc[i][j] = {0.f, 0.f, 0.f, 0.f};

  const bf16* Ab = A + (size_t)bm * 128 * K;
  const float* Wb = Wp + (size_t)bn * 128 * K;

  for (int k0 = 0; k0 < K; k0 += BK) {
    __syncthreads();
#pragma unroll
    for (int i = 0; i < 4; ++i) {
      const int c = t + i * 256;
      const int row = c >> 3, slot = c & 7;
      gload_lds16(Ab + (size_t)row * K + k0 + ((slot ^ (row & 7)) << 3), &As[c * 8]);
    }
#pragma unroll
    for (int i = 0; i < 4; ++i) {
      const int c = t + i * 256;
      const int row = c >> 3, slot = c & 7;
      const float4* wp = (const float4*)(Wb + (size_t)row * K + k0 + slot * 8);
      float4 w0 = wp[0], w1 = wp[1];
      bf16x8 pk;
      pk[0] = (bf16)w0.x; pk[1] = (bf16)w0.y; pk[2] = (bf16)w0.z; pk[3] = (bf16)w0.w;
      pk[4] = (bf16)w1.x; pk[5] = (bf16)w1.y; pk[6] = (bf16)w1.z; pk[7] = (bf16)w1.w;
      *(bf16x8*)&Bs[row * BK + ((slot ^ (row & 7)) << 3)] = pk;
    }
    __syncthreads();
#pragma unroll
    for (int ks = 0; ks < 2; ++ks) {
      bf16x8 af[4], bfv[4];
#pragma unroll
      for (int mt = 0; mt < 4; ++mt) {
        const int row = wm * 64 + mt * 16 + l15;
        af[mt] = *(const bf16x8*)&As[row * BK + (((ks * 4 + g) ^ (row & 7)) << 3)];
      }
#pragma unroll
      for (int nt = 0; nt < 4; ++nt) {
        const int row = wn * 64 + nt * 16 + l15;
        bfv[nt] = *(const bf16x8*)&Bs[row * BK + (((ks * 4 + g) ^ (row & 7)) << 3)];
      }
#pragma unroll
      for (int mt = 0; mt < 4; ++mt)
#pragma unroll
        for (int nt = 0; nt < 4; ++nt)
          acc[mt][nt] = __builtin_amdgcn_mfma_f32_16x16x32_bf16(af[mt], bfv[nt], acc[mt][nt], 0, 0, 0);
    }
  }

  const int row0 = bm * 128 + wm * 64;
  const int col0 = bn * 128 + wn * 64;
#pragma unroll
  for (int nt = 0; nt < 4; ++nt) {
    const int col = col0 + nt * 16 + l15;
    const float bv = bias ? bias[col] : 0.f;
#pragma unroll
    for (int mt = 0; mt < 4; ++mt) {
#pragma unroll
      for (int r = 0; r < 4; ++r) {
        const int rowi = row0 + mt * 16 + g * 4 + r;
        const size_t idx = (size_t)rowi * N + col;
        float v = acc[mt][nt][r] + bv;
        if constexpr (EPI == 0) {
          ((bf16*)out)[idx] = (bf16)v;
        } else if constexpr (EPI == 1) {
          v += ((const float*)ext)[idx];
          ((bf16*)out)[idx] = (bf16)v;
        } else if constexpr (EPI == 2) {
          const float gv = (float)((const bf16*)ext)[idx];
          const float sg = gv / (1.f + __expf(-gv));
          ((bf16*)out)[idx] = (bf16)(sg * v);
        } else {
          v += (float)((const bf16*)ext)[idx];
          ((float*)out)[idx] = v;
        }
      }
    }
  }
}

// ---------------- Flash attention (no mask, GQA 4:1); q/k from qkvb, V from vT ----------
__global__ __launch_bounds__(256, 2) void attn_k(const bf16* __restrict__ qkvb,
                                                 const bf16* __restrict__ vT,
                                                 bf16* __restrict__ ob) {
  __shared__ bf16 Ks[64 * 128];   // [kv][d], 256B rows, 16B-slot ^ (kv&15)
  __shared__ bf16 Vt[128 * 64];   // [d][kv], 128B rows, 16B-slot ^ (d&7)
  __shared__ bf16 Ps[4][32 * 64]; // per-wave [q][kv], slot ^ (q&7)
  const int t = threadIdx.x, lane = t & 63, w = t >> 6;
  const int g = lane >> 4, l15 = lane & 15;
  const int b = blockIdx.z, h = blockIdx.y;
  const int kvh = h >> 2;
  const int q0 = blockIdx.x * 128 + w * 32;
  const bf16* vTb = vT + (size_t)(b * KVH_ + kvh) * HD_ * S_;

  bf16x8 qf[2][4];  // B-frags: Q[q = qt*16+l15][d = ks*32+g*8 ..+7]
#pragma unroll
  for (int qt = 0; qt < 2; ++qt)
#pragma unroll
    for (int ks = 0; ks < 4; ++ks)
      qf[qt][ks] = *(const bf16x8*)(qkvb + (size_t)(b * S_ + q0 + qt * 16 + l15) * QKS + h * HD_ + ks * 32 + g * 8);

  f32x4 o[8][2];
#pragma unroll
  for (int i = 0; i < 8; ++i) { o[i][0] = {0.f,0.f,0.f,0.f}; o[i][1] = {0.f,0.f,0.f,0.f}; }
  float mA[2] = {-1e30f, -1e30f}, lA[2] = {0.f, 0.f};

  for (int s0 = 0; s0 < S_; s0 += 64) {
    __syncthreads();
#pragma unroll
    for (int i = 0; i < 4; ++i) {  // K tile via global_load_lds, source-swizzled
      const int c = t + i * 256;
      const int row = c >> 4, slot = c & 15;
      gload_lds16(qkvb + (size_t)(b * S_ + s0 + row) * QKS + 2048 + kvh * HD_ + ((slot ^ (row & 15)) << 3),
                  &Ks[c * 8]);
    }
#pragma unroll
    for (int i = 0; i < 4; ++i) {  // V^T tile via global_load_lds from vT, source-swizzled
      const int c = t + i * 256;
      const int row = c >> 3, slot = c & 7;   // row = d, 8 slots of 8 along s
      gload_lds16(vTb + (size_t)row * S_ + s0 + ((slot ^ (row & 7)) << 3), &Vt[c * 8]);
    }
    __syncthreads();

    f32x4 sc[2][4];
#pragma unroll
    for (int qt = 0; qt < 2; ++qt)
#pragma unroll
      for (int c = 0; c < 4; ++c) sc[qt][c] = {0.f,0.f,0.f,0.f};
    __builtin_amdgcn_s_setprio(1);
#pragma unroll
    for (int ks = 0; ks < 4; ++ks) {
      bf16x8 kf[4];
#pragma unroll
      for (int c = 0; c < 4; ++c) {
        const int kv = c * 16 + l15;
        kf[c] = *(const bf16x8*)&Ks[kv * 128 + (((ks * 4 + g) ^ (kv & 15)) << 3)];
      }
#pragma unroll
      for (int c = 0; c < 4; ++c) {
        sc[0][c] = __builtin_amdgcn_mfma_f32_16x16x32_bf16(kf[c], qf[0][ks], sc[0][c], 0, 0, 0);
        sc[1][c] = __builtin_amdgcn_mfma_f32_16x16x32_bf16(kf[c], qf[1][ks], sc[1][c], 0, 0, 0);
      }
    }
    __builtin_amdgcn_s_setprio(0);

    float corr[2];
#pragma unroll
    for (int qt = 0; qt < 2; ++qt) {   // lane-local online softmax (lane's q = qt*16+l15)
      float tm = sc[qt][0][0];
#pragma unroll
      for (int c = 0; c < 4; ++c)
#pragma unroll
        for (int r = 0; r < 4; ++r) tm = fmaxf(tm, sc[qt][c][r]);
      tm = fmaxf(tm, __shfl_xor(tm, 16));
      tm = fmaxf(tm, __shfl_xor(tm, 32));
      const float mn = fmaxf(mA[qt], tm);
      corr[qt] = __expf((mA[qt] - mn) * SCALE_);
      mA[qt] = mn;
      float ps = 0.f;
      const int q = qt * 16 + l15;
#pragma unroll
      for (int c = 0; c < 4; ++c)
#pragma unroll
        for (int r = 0; r < 4; ++r) {
          const float p = __expf((sc[qt][c][r] - mn) * SCALE_);
          ps += p;
          const int kv = c * 16 + g * 4 + r;
          Ps[w][q * 64 + (((kv >> 3) ^ (q & 7)) << 3) + (kv & 7)] = (bf16)p;
        }
      ps += __shfl_xor(ps, 16);
      ps += __shfl_xor(ps, 32);
      lA[qt] = lA[qt] * corr[qt] + ps;
#pragma unroll
      for (int dt = 0; dt < 8; ++dt) o[dt][qt] *= corr[qt];
    }
    asm volatile("s_waitcnt lgkmcnt(0)" ::: "memory");  // P round-trip fence (wave-private)
    __builtin_amdgcn_s_setprio(1);
#pragma unroll
    for (int ks = 0; ks < 2; ++ks) {
      bf16x8 pf[2];
#pragma unroll
      for (int qt = 0; qt < 2; ++qt) {
        const int q = qt * 16 + l15;
        pf[qt] = *(const bf16x8*)&Ps[w][q * 64 + (((ks * 4 + g) ^ (q & 7)) << 3)];
      }
#pragma unroll
      for (int dt = 0; dt < 8; ++dt) {
        const int d = dt * 16 + l15;
        const bf16x8 vf = *(const bf16x8*)&Vt[d * 64 + (((ks * 4 + g) ^ (d & 7)) << 3)];
        o[dt][0] = __builtin_amdgcn_mfma_f32_16x16x32_bf16(vf, pf[0], o[dt][0], 0, 0, 0);
        o[dt][1] = __builtin_amdgcn_mfma_f32_16x16x32_bf16(vf, pf[1], o[dt][1], 0, 0, 0);
      }
    }
    __builtin_amdgcn_s_setprio(0);
  }

  // normalize + coalesced store via per-wave LDS bounce (reuse Ks/Vt)
  const float inv0 = 1.f / lA[0], inv1 = 1.f / lA[1];
  __syncthreads();
  bf16* bb = (w < 2) ? &Ks[(w & 1) * 4096] : &Vt[(w & 1) * 4096];
#pragma unroll
  for (int dt = 0; dt < 8; ++dt)
#pragma unroll
    for (int qt = 0; qt < 2; ++qt) {
      const float iv = qt ? inv1 : inv0;
      bf16x4 pk;
#pragma unroll
      for (int r = 0; r < 4; ++r) pk[r] = (bf16)(o[dt][qt][r] * iv);
      const int q = qt * 16 + l15;
      const int s16 = (dt * 2 + (g >> 1)) ^ (q & 15);     // 16 slots per 256B row
      *(bf16x4*)&bb[q * 128 + (s16 << 3) + ((g & 1) << 2)] = pk;
    }
  asm volatile("s_waitcnt lgkmcnt(0)" ::: "memory");
#pragma unroll
  for (int it = 0; it < 8; ++it) {
    const int c = lane + it * 64;
    const int q = c >> 4, s16 = c & 15;
    const bf16x8 vv = *(const bf16x8*)&bb[q * 128 + ((s16 ^ (q & 15)) << 3)];
    *(bf16x8*)(ob + (size_t)(b * S_ + q0 + q) * E_ + h * HD_ + s16 * 8) = vv;
  }
}

// ---------------- launcher ----------------
extern "C" void kernel_launch(void* const* d_in, const int* in_sizes, int n_in,
                              void* d_out, int out_size, void* d_ws, size_t ws_size,
                              hipStream_t stream) {
  const float* x   = (const float*)d_in[0];
  // d_in[1] = attn_mask: reference never applies it
  const float* wq  = (const float*)d_in[2];
  const float* bq  = (const float*)d_in[3];
  const float* wkv = (const float*)d_in[4];
  const float* bkv = (const float*)d_in[5];
  const float* wo  = (const float*)d_in[6];
  const float* wg  = (const float*)d_in[7];
  const float* wu  = (const float*)d_in[8];
  const float* wd  = (const float*)d_in[9];
  const float* n1  = (const float*)d_in[10];
  const float* n2  = (const float*)d_in[11];
  float* out = (float*)d_out;
  char* ws = (char*)d_ws;
  // Activations:
  bf16* y    = (bf16*)(ws);                   // 16 MiB [attn-out o; then y2]
  bf16* qkvb = (bf16*)(ws + (16ull << 20));   // 24 MiB fused q|k|v, row stride 3072
  bf16* x1   = (bf16*)(ws + (40ull << 20));   // 16 MiB (bf16 residual)
  bf16* gh   = (bf16*)(ws + (56ull << 20));   // 64 MiB (h); first 4 MiB aliased as vT pre-gu
  bf16* vT   = gh;                            // 4 MiB, dead once gu writes gh
  bf16* o    = y;
  bf16* y2   = y;
  // Tier A: bf16 weight mirrors, contiguous 116 MiB at +120
  bf16* wqkvb = (bf16*)(ws + (120ull << 20)); // 12 MiB: wq rows then wkv rows
  bf16* wob   = (bf16*)(ws + (132ull << 20)); // 8 MiB
  bf16* wgb   = (bf16*)(ws + (140ull << 20)); // 32 MiB
  bf16* wub   = (bf16*)(ws + (172ull << 20)); // 32 MiB
  bf16* wdb   = (bf16*)(ws + (204ull << 20)); // 32 MiB -> end 236 MiB
  const int M = B_ * S_;  // 4096
  const bool tierA = ws_size >= (236ull << 20);

  if (tierA)
    cvt6_k<<<2048, 256, 0, stream>>>(wq, wkv, wo, wg, wu, wd, wqkvb);

  rmsnorm_k<float><<<M, 256, 0, stream>>>(x, n1, y);
  if (tierA) {
    gemm_n2<0, true><<<dim3(QKS / 256, M / 128), 256, 0, stream>>>(
        y, wqkvb, bq, bkv, nullptr, qkvb, M, QKS, E_);
  } else {
    gemm_bt<0><<<dim3(E_ / 128, M / 128), 256, 0, stream>>>(y, wq, bq, nullptr, qkvb, M, QKS, E_);
    gemm_bt<0><<<dim3(KVROW / 128, M / 128), 256, 0, stream>>>(y, wkv, bkv, nullptr, qkvb + 2048, M, QKS, E_);
  }
  rope_k<<<(B_ * S_ * (H_ + KVH_) * 64) / 256, 256, 0, stream>>>(qkvb);
  vtrans_k<<<dim3(S_ / 64, KVH_, B_), 256, 0, stream>>>(qkvb, vT);
  attn_k<<<dim3(S_ / 128, H_, B_), 256, 0, stream>>>(qkvb, vT, o);
  if (tierA) {
    gemm_n2<1, false><<<dim3(E_ / 256, M / 128), 256, 0, stream>>>(
        o, wob, nullptr, nullptr, x, x1, M, E_, E_);
    rmsnorm_k<bf16><<<M, 256, 0, stream>>>(x1, n2, y2);
    gemm_gu<<<dim3(I_ / 128, M / 128), 256, 0, stream>>>(y2, wgb, wub, gh, M, I_, E_);
    gemm_n2<3, false><<<dim3(E_ / 256, M / 128), 256, 0, stream>>>(
        gh, wdb, nullptr, nullptr, x1, out, M, E_, I_);
  } else {
    gemm_bt<1><<<dim3(E_ / 128, M / 128), 256, 0, stream>>>(o, wo, nullptr, x, x1, M, E_, E_);
    rmsnorm_k<bf16><<<M, 256, 0, stream>>>(x1, n2, y2);
    gemm_bt<0><<<dim3(I_ / 128, M / 128), 256, 0, stream>>>(y2, wg, nullptr, nullptr, gh, M, I_, E_);
    gemm_bt<2><<<dim3(I_ / 128, M / 128), 256, 0, stream>>>(y2, wu, nullptr, gh, gh, M, I_, E_);
    gemm_bt<3><<<dim3(E_ / 128, M / 128), 256, 0, stream>>>(gh, wd, nullptr, x1, out, M, E_, I_);
  }
}

// Round 16
// 708.228 us; speedup vs baseline: 1.1300x; 1.1300x over previous
//
#include <hip/hip_runtime.h>

typedef __bf16 bf16;
typedef __bf16 bf16x8 __attribute__((ext_vector_type(8)));
typedef __bf16 bf16x4 __attribute__((ext_vector_type(4)));
typedef float f32x4 __attribute__((ext_vector_type(4)));

#define DEV __device__ __forceinline__

constexpr int B_ = 2, S_ = 2048, E_ = 2048, H_ = 16, KVH_ = 4, HD_ = 128, I_ = 8192;
constexpr int KVROW = 2 * KVH_ * HD_;   // 1024
constexpr int QKS = 3072;               // fused qkv row stride
constexpr float EPS_ = 1e-6f;
constexpr float SCALE_ = 0.08838834764831845f;  // 128^-0.5

DEV void gload_lds16(const bf16* g, bf16* l) {
  __builtin_amdgcn_global_load_lds(
      (const __attribute__((address_space(1))) void*)g,
      (__attribute__((address_space(3))) void*)l, 16, 0, 0);
}

// ---------------- fused f32 -> bf16 conversion of all 6 weights ----------------
__global__ __launch_bounds__(256) void cvt6_k(const float* __restrict__ s0, const float* __restrict__ s1,
                                              const float* __restrict__ s2, const float* __restrict__ s3,
                                              const float* __restrict__ s4, const float* __restrict__ s5,
                                              bf16* __restrict__ dst) {
  constexpr size_t N0 = 4194304, N1 = 2097152, N2 = 4194304,
                   N3 = 16777216, N4 = 16777216, N5 = 16777216;
  constexpr size_t TOT = N0 + N1 + N2 + N3 + N4 + N5;
  for (size_t i = ((size_t)blockIdx.x * 256 + threadIdx.x) * 8; i < TOT;
       i += (size_t)gridDim.x * 256 * 8) {
    size_t off = i; const float* sp;
    if (off < N0) sp = s0;
    else if ((off -= N0) < N1) sp = s1;
    else if ((off -= N1) < N2) sp = s2;
    else if ((off -= N2) < N3) sp = s3;
    else if ((off -= N3) < N4) sp = s4;
    else { off -= N4; sp = s5; }
    const float4* p = (const float4*)(sp + off);
    float4 a = p[0], b = p[1];
    bf16x8 o;
    o[0]=(bf16)a.x; o[1]=(bf16)a.y; o[2]=(bf16)a.z; o[3]=(bf16)a.w;
    o[4]=(bf16)b.x; o[5]=(bf16)b.y; o[6]=(bf16)b.z; o[7]=(bf16)b.w;
    *(bf16x8*)(dst + i) = o;
  }
}

// ---------------- RMSNorm: one block per row of E_=2048 -> bf16 out ----------------
template <typename InT>
__global__ __launch_bounds__(256) void rmsnorm_k(const InT* __restrict__ x,
                                                 const float* __restrict__ w,
                                                 bf16* __restrict__ y) {
  const int row = blockIdx.x, t = threadIdx.x;
  const size_t base = (size_t)row * E_ + t * 8;
  float v[8];
  if constexpr (sizeof(InT) == 2) {
    bf16x8 d = *(const bf16x8*)(x + base);
#pragma unroll
    for (int j = 0; j < 8; ++j) v[j] = (float)d[j];
  } else {
    const float4* p = (const float4*)(x + base);
    float4 a = p[0], b2 = p[1];
    v[0]=a.x; v[1]=a.y; v[2]=a.z; v[3]=a.w; v[4]=b2.x; v[5]=b2.y; v[6]=b2.z; v[7]=b2.w;
  }
  float ss = 0.f;
#pragma unroll
  for (int j = 0; j < 8; ++j) ss += v[j] * v[j];
#pragma unroll
  for (int off = 32; off; off >>= 1) ss += __shfl_xor(ss, off);
  __shared__ float red[4];
  if ((t & 63) == 0) red[t >> 6] = ss;
  __syncthreads();
  ss = red[0] + red[1] + red[2] + red[3];
  const float sc = rsqrtf(ss * (1.0f / E_) + EPS_);
  const float4* wp = (const float4*)(w + t * 8);
  float4 wa = wp[0], wb = wp[1];
  float wv[8] = {wa.x, wa.y, wa.z, wa.w, wb.x, wb.y, wb.z, wb.w};
  bf16x8 o;
#pragma unroll
  for (int j = 0; j < 8; ++j) o[j] = (bf16)(v[j] * sc * wv[j]);
  *(bf16x8*)(y + base) = o;
}

// ---------------- RoPE in place on fused qkv buffer [M][3072] ----------------
__global__ __launch_bounds__(256) void rope_k(bf16* __restrict__ qkvb) {
  const int gid = blockIdx.x * 256 + threadIdx.x;   // B*S*(H+KV)*64 total
  const int d = gid & 63;
  const int r = gid >> 6;
  const int hh = r % (H_ + KVH_);
  const int s = (r / (H_ + KVH_)) % S_;
  const int b = r / ((H_ + KVH_) * S_);
  bf16* p = qkvb + (size_t)(b * S_ + s) * QKS +
            (hh < H_ ? hh * HD_ : 2048 + (hh - H_) * HD_);
  const float invf = exp2f(-(float)d * (13.287712379549449f / 64.f)); // 10000^(-d/64)
  float sn, cs;
  sincosf((float)s * invf, &sn, &cs);
  const float x1 = (float)p[d], x2 = (float)p[d + 64];
  p[d] = (bf16)(x1 * cs - x2 * sn);
  p[d + 64] = (bf16)(x2 * cs + x1 * sn);
}

// ---------------- V transpose: qkvb[..][2560+kvh*128+d] -> vT[b][kvh][d][s] ----------------
__global__ __launch_bounds__(256) void vtrans_k(const bf16* __restrict__ qkvb,
                                                bf16* __restrict__ vT) {
  __shared__ bf16 lds[64 * 136];
  const int t = threadIdx.x;
  const int s0 = blockIdx.x * 64, kvh = blockIdx.y, b = blockIdx.z;
#pragma unroll
  for (int i = 0; i < 4; ++i) {   // stage 64 s-rows x 128 d, coalesced
    const int c = t + i * 256;
    const int row = c >> 4, slot = c & 15;
    *(bf16x8*)&lds[row * 136 + slot * 8] =
        *(const bf16x8*)(qkvb + (size_t)(b * S_ + s0 + row) * QKS + 2560 + kvh * HD_ + slot * 8);
  }
  __syncthreads();
#pragma unroll
  for (int i = 0; i < 4; ++i) {   // write 128 d-rows x 64 s, coalesced
    const int c = t + i * 256;
    const int d = c >> 3, ss = c & 7;
    bf16x8 pk;
#pragma unroll
    for (int j = 0; j < 8; ++j) pk[j] = lds[(ss * 8 + j) * 136 + d];
    *(bf16x8*)(vT + (size_t)((b * KVH_ + kvh) * HD_ + d) * S_ + s0 + ss * 8) = pk;
  }
}

// ---------------- Fused gate+up GEMM (r11 proven): h = silu(A@Wg^T)*(A@Wu^T) --------
__global__ __launch_bounds__(256, 2) void gemm_gu(const bf16* __restrict__ A,
                                                  const bf16* __restrict__ Wg,
                                                  const bf16* __restrict__ Wu,
                                                  bf16* __restrict__ out,
                                                  int M, int N, int K) {
  constexpr int BK = 64;
  __shared__ bf16 As[128 * BK];
  __shared__ bf16 Bg[128 * BK];
  __shared__ bf16 Bu[128 * BK];
  const int t = threadIdx.x, lane = t & 63, w = t >> 6;
  const int g = lane >> 4, l15 = lane & 15;
  const int bm = blockIdx.y, bn = blockIdx.x;   // r11 orientation (measured best)
  const int wm = w >> 1, wn = w & 1;
  f32x4 ag[4][4], au[4][4];
#pragma unroll
  for (int i = 0; i < 4; ++i)
#pragma unroll
    for (int j = 0; j < 4; ++j) { ag[i][j] = {0.f,0.f,0.f,0.f}; au[i][j] = {0.f,0.f,0.f,0.f}; }

  const bf16* Ab  = A  + (size_t)bm * 128 * K;
  const bf16* Wgb = Wg + (size_t)bn * 128 * K;
  const bf16* Wub = Wu + (size_t)bn * 128 * K;

  for (int k0 = 0; k0 < K; k0 += BK) {
    __syncthreads();
#pragma unroll
    for (int i = 0; i < 4; ++i) {
      const int c = t + i * 256;
      const int row = c >> 3, slot = c & 7;
      const size_t goff = (size_t)row * K + k0 + ((slot ^ (row & 7)) << 3);
      gload_lds16(Ab + goff, &As[c * 8]);
      gload_lds16(Wgb + goff, &Bg[c * 8]);
      gload_lds16(Wub + goff, &Bu[c * 8]);
    }
    __syncthreads();
#pragma unroll
    for (int ks = 0; ks < 2; ++ks) {
      bf16x8 af[4], bgv[4], buv[4];
#pragma unroll
      for (int mt = 0; mt < 4; ++mt) {
        const int row = wm * 64 + mt * 16 + l15;
        af[mt] = *(const bf16x8*)&As[row * BK + (((ks * 4 + g) ^ (row & 7)) << 3)];
      }
#pragma unroll
      for (int nt = 0; nt < 4; ++nt) {
        const int row = wn * 64 + nt * 16 + l15;
        const int off = row * BK + (((ks * 4 + g) ^ (row & 7)) << 3);
        bgv[nt] = *(const bf16x8*)&Bg[off];
        buv[nt] = *(const bf16x8*)&Bu[off];
      }
#pragma unroll
      for (int mt = 0; mt < 4; ++mt)
#pragma unroll
        for (int nt = 0; nt < 4; ++nt) {
          ag[mt][nt] = __builtin_amdgcn_mfma_f32_16x16x32_bf16(af[mt], bgv[nt], ag[mt][nt], 0, 0, 0);
          au[mt][nt] = __builtin_amdgcn_mfma_f32_16x16x32_bf16(af[mt], buv[nt], au[mt][nt], 0, 0, 0);
        }
    }
  }

  const int row0 = bm * 128 + wm * 64;
  const int col0 = bn * 128 + wn * 64;
#pragma unroll
  for (int nt = 0; nt < 4; ++nt) {
    const int col = col0 + nt * 16 + l15;
#pragma unroll
    for (int mt = 0; mt < 4; ++mt) {
#pragma unroll
      for (int r = 0; r < 4; ++r) {
        const int rowi = row0 + mt * 16 + g * 4 + r;
        const float gv = ag[mt][nt][r];
        const float hv = (gv / (1.f + __expf(-gv))) * au[mt][nt][r];
        out[(size_t)rowi * N + col] = (bf16)hv;
      }
    }
  }
}

// ---------------- GEMM 128x128 (m97 structure; proven config: >=512 blocks, 2/CU) ----
// WB: W pre-converted bf16 (global_load_lds) vs f32 (reg-stage + cvt)
// EPI: 0 = (+dual bias) -> bf16; 1 = + f32 ext -> bf16; 2 = silu(bf16 ext)*acc -> bf16;
//      3 = + bf16 ext -> f32 out (down, final)
template <int EPI, bool WB>
__global__ __launch_bounds__(256, 2) void gemm_bt(const bf16* __restrict__ A,
                                                  const void* __restrict__ Wp,
                                                  const float* __restrict__ bias0,
                                                  const float* __restrict__ bias1,
                                                  const void* __restrict__ ext,
                                                  void* __restrict__ out,
                                                  int M, int N, int K) {
  constexpr int BK = 64;
  __shared__ bf16 As[128 * BK];
  __shared__ bf16 Bs[128 * BK];
  const int t = threadIdx.x, lane = t & 63, w = t >> 6;
  const int g = lane >> 4, l15 = lane & 15;
  const int bm = blockIdx.y, bn = blockIdx.x;
  const int wm = w >> 1, wn = w & 1;
  f32x4 acc[4][4];
#pragma unroll
  for (int i = 0; i < 4; ++i)
#pragma unroll
    for (int j = 0; j < 4; ++j) acc[i][j] = {0.f, 0.f, 0.f, 0.f};

  const bf16* Ab = A + (size_t)bm * 128 * K;

  for (int k0 = 0; k0 < K; k0 += BK) {
    __syncthreads();
#pragma unroll
    for (int i = 0; i < 4; ++i) {
      const int c = t + i * 256;
      const int row = c >> 3, slot = c & 7;
      gload_lds16(Ab + (size_t)row * K + k0 + ((slot ^ (row & 7)) << 3), &As[c * 8]);
    }
    if constexpr (WB) {
      const bf16* Wb = (const bf16*)Wp + (size_t)bn * 128 * K;
#pragma unroll
      for (int i = 0; i < 4; ++i) {
        const int c = t + i * 256;
        const int row = c >> 3, slot = c & 7;
        gload_lds16(Wb + (size_t)row * K + k0 + ((slot ^ (row & 7)) << 3), &Bs[c * 8]);
      }
    } else {
      const float* Wb = (const float*)Wp + (size_t)bn * 128 * K;
#pragma unroll
      for (int i = 0; i < 4; ++i) {
        const int c = t + i * 256;
        const int row = c >> 3, slot = c & 7;
        const float4* wp = (const float4*)(Wb + (size_t)row * K + k0 + slot * 8);
        float4 w0 = wp[0], w1 = wp[1];
        bf16x8 pk;
        pk[0] = (bf16)w0.x; pk[1] = (bf16)w0.y; pk[2] = (bf16)w0.z; pk[3] = (bf16)w0.w;
        pk[4] = (bf16)w1.x; pk[5] = (bf16)w1.y; pk[6] = (bf16)w1.z; pk[7] = (bf16)w1.w;
        *(bf16x8*)&Bs[row * BK + ((slot ^ (row & 7)) << 3)] = pk;
      }
    }
    __syncthreads();
#pragma unroll
    for (int ks = 0; ks < 2; ++ks) {
      bf16x8 af[4], bfv[4];
#pragma unroll
      for (int mt = 0; mt < 4; ++mt) {
        const int row = wm * 64 + mt * 16 + l15;
        af[mt] = *(const bf16x8*)&As[row * BK + (((ks * 4 + g) ^ (row & 7)) << 3)];
      }
#pragma unroll
      for (int nt = 0; nt < 4; ++nt) {
        const int row = wn * 64 + nt * 16 + l15;
        bfv[nt] = *(const bf16x8*)&Bs[row * BK + (((ks * 4 + g) ^ (row & 7)) << 3)];
      }
#pragma unroll
      for (int mt = 0; mt < 4; ++mt)
#pragma unroll
        for (int nt = 0; nt < 4; ++nt)
          acc[mt][nt] = __builtin_amdgcn_mfma_f32_16x16x32_bf16(af[mt], bfv[nt], acc[mt][nt], 0, 0, 0);
    }
  }

  const int row0 = bm * 128 + wm * 64;
  const int col0 = bn * 128 + wn * 64;
#pragma unroll
  for (int nt = 0; nt < 4; ++nt) {
    const int col = col0 + nt * 16 + l15;
    float bv = 0.f;
    if constexpr (EPI == 0) {
      if (bias0) bv = (col < 2048 || !bias1) ? bias0[col] : bias1[col - 2048];
    }
#pragma unroll
    for (int mt = 0; mt < 4; ++mt) {
#pragma unroll
      for (int r = 0; r < 4; ++r) {
        const int rowi = row0 + mt * 16 + g * 4 + r;
        const size_t idx = (size_t)rowi * N + col;
        float v = acc[mt][nt][r] + bv;
        if constexpr (EPI == 0) {
          ((bf16*)out)[idx] = (bf16)v;
        } else if constexpr (EPI == 1) {
          v += ((const float*)ext)[idx];
          ((bf16*)out)[idx] = (bf16)v;
        } else if constexpr (EPI == 2) {
          const float gv = (float)((const bf16*)ext)[idx];
          const float sg = gv / (1.f + __expf(-gv));
          ((bf16*)out)[idx] = (bf16)(sg * v);
        } else {
          v += (float)((const bf16*)ext)[idx];
          ((float*)out)[idx] = v;
        }
      }
    }
  }
}

// ---------------- Flash attention (no mask, GQA 4:1); q/k from qkvb, V from vT ----------
__global__ __launch_bounds__(256, 2) void attn_k(const bf16* __restrict__ qkvb,
                                                 const bf16* __restrict__ vT,
                                                 bf16* __restrict__ ob) {
  __shared__ bf16 Ks[64 * 128];   // [kv][d], 256B rows, 16B-slot ^ (kv&15)
  __shared__ bf16 Vt[128 * 64];   // [d][kv], 128B rows, 16B-slot ^ (d&7)
  __shared__ bf16 Ps[4][32 * 64]; // per-wave [q][kv], slot ^ (q&7)
  const int t = threadIdx.x, lane = t & 63, w = t >> 6;
  const int g = lane >> 4, l15 = lane & 15;
  const int b = blockIdx.z, h = blockIdx.y;
  const int kvh = h >> 2;
  const int q0 = blockIdx.x * 128 + w * 32;
  const bf16* vTb = vT + (size_t)(b * KVH_ + kvh) * HD_ * S_;

  bf16x8 qf[2][4];  // B-frags: Q[q = qt*16+l15][d = ks*32+g*8 ..+7]
#pragma unroll
  for (int qt = 0; qt < 2; ++qt)
#pragma unroll
    for (int ks = 0; ks < 4; ++ks)
      qf[qt][ks] = *(const bf16x8*)(qkvb + (size_t)(b * S_ + q0 + qt * 16 + l15) * QKS + h * HD_ + ks * 32 + g * 8);

  f32x4 o[8][2];
#pragma unroll
  for (int i = 0; i < 8; ++i) { o[i][0] = {0.f,0.f,0.f,0.f}; o[i][1] = {0.f,0.f,0.f,0.f}; }
  float mA[2] = {-1e30f, -1e30f}, lA[2] = {0.f, 0.f};

  for (int s0 = 0; s0 < S_; s0 += 64) {
    __syncthreads();
#pragma unroll
    for (int i = 0; i < 4; ++i) {  // K tile via global_load_lds, source-swizzled
      const int c = t + i * 256;
      const int row = c >> 4, slot = c & 15;
      gload_lds16(qkvb + (size_t)(b * S_ + s0 + row) * QKS + 2048 + kvh * HD_ + ((slot ^ (row & 15)) << 3),
                  &Ks[c * 8]);
    }
#pragma unroll
    for (int i = 0; i < 4; ++i) {  // V^T tile via global_load_lds from vT, source-swizzled
      const int c = t + i * 256;
      const int row = c >> 3, slot = c & 7;   // row = d, 8 slots of 8 along s
      gload_lds16(vTb + (size_t)row * S_ + s0 + ((slot ^ (row & 7)) << 3), &Vt[c * 8]);
    }
    __syncthreads();

    f32x4 sc[2][4];
#pragma unroll
    for (int qt = 0; qt < 2; ++qt)
#pragma unroll
      for (int c = 0; c < 4; ++c) sc[qt][c] = {0.f,0.f,0.f,0.f};
    __builtin_amdgcn_s_setprio(1);
#pragma unroll
    for (int ks = 0; ks < 4; ++ks) {
      bf16x8 kf[4];
#pragma unroll
      for (int c = 0; c < 4; ++c) {
        const int kv = c * 16 + l15;
        kf[c] = *(const bf16x8*)&Ks[kv * 128 + (((ks * 4 + g) ^ (kv & 15)) << 3)];
      }
#pragma unroll
      for (int c = 0; c < 4; ++c) {
        sc[0][c] = __builtin_amdgcn_mfma_f32_16x16x32_bf16(kf[c], qf[0][ks], sc[0][c], 0, 0, 0);
        sc[1][c] = __builtin_amdgcn_mfma_f32_16x16x32_bf16(kf[c], qf[1][ks], sc[1][c], 0, 0, 0);
      }
    }
    __builtin_amdgcn_s_setprio(0);

    float corr[2];
#pragma unroll
    for (int qt = 0; qt < 2; ++qt) {   // lane-local online softmax (lane's q = qt*16+l15)
      float tm = sc[qt][0][0];
#pragma unroll
      for (int c = 0; c < 4; ++c)
#pragma unroll
        for (int r = 0; r < 4; ++r) tm = fmaxf(tm, sc[qt][c][r]);
      tm = fmaxf(tm, __shfl_xor(tm, 16));
      tm = fmaxf(tm, __shfl_xor(tm, 32));
      const float mn = fmaxf(mA[qt], tm);
      corr[qt] = __expf((mA[qt] - mn) * SCALE_);
      mA[qt] = mn;
      float ps = 0.f;
      const int q = qt * 16 + l15;
#pragma unroll
      for (int c = 0; c < 4; ++c)
#pragma unroll
        for (int r = 0; r < 4; ++r) {
          const float p = __expf((sc[qt][c][r] - mn) * SCALE_);
          ps += p;
          const int kv = c * 16 + g * 4 + r;
          Ps[w][q * 64 + (((kv >> 3) ^ (q & 7)) << 3) + (kv & 7)] = (bf16)p;
        }
      ps += __shfl_xor(ps, 16);
      ps += __shfl_xor(ps, 32);
      lA[qt] = lA[qt] * corr[qt] + ps;
#pragma unroll
      for (int dt = 0; dt < 8; ++dt) o[dt][qt] *= corr[qt];
    }
    asm volatile("s_waitcnt lgkmcnt(0)" ::: "memory");  // P round-trip fence (wave-private)
    __builtin_amdgcn_s_setprio(1);
#pragma unroll
    for (int ks = 0; ks < 2; ++ks) {
      bf16x8 pf[2];
#pragma unroll
      for (int qt = 0; qt < 2; ++qt) {
        const int q = qt * 16 + l15;
        pf[qt] = *(const bf16x8*)&Ps[w][q * 64 + (((ks * 4 + g) ^ (q & 7)) << 3)];
      }
#pragma unroll
      for (int dt = 0; dt < 8; ++dt) {
        const int d = dt * 16 + l15;
        const bf16x8 vf = *(const bf16x8*)&Vt[d * 64 + (((ks * 4 + g) ^ (d & 7)) << 3)];
        o[dt][0] = __builtin_amdgcn_mfma_f32_16x16x32_bf16(vf, pf[0], o[dt][0], 0, 0, 0);
        o[dt][1] = __builtin_amdgcn_mfma_f32_16x16x32_bf16(vf, pf[1], o[dt][1], 0, 0, 0);
      }
    }
    __builtin_amdgcn_s_setprio(0);
  }

  // normalize + coalesced store via per-wave LDS bounce (reuse Ks/Vt)
  const float inv0 = 1.f / lA[0], inv1 = 1.f / lA[1];
  __syncthreads();
  bf16* bb = (w < 2) ? &Ks[(w & 1) * 4096] : &Vt[(w & 1) * 4096];
#pragma unroll
  for (int dt = 0; dt < 8; ++dt)
#pragma unroll
    for (int qt = 0; qt < 2; ++qt) {
      const float iv = qt ? inv1 : inv0;
      bf16x4 pk;
#pragma unroll
      for (int r = 0; r < 4; ++r) pk[r] = (bf16)(o[dt][qt][r] * iv);
      const int q = qt * 16 + l15;
      const int s16 = (dt * 2 + (g >> 1)) ^ (q & 15);     // 16 slots per 256B row
      *(bf16x4*)&bb[q * 128 + (s16 << 3) + ((g & 1) << 2)] = pk;
    }
  asm volatile("s_waitcnt lgkmcnt(0)" ::: "memory");
#pragma unroll
  for (int it = 0; it < 8; ++it) {
    const int c = lane + it * 64;
    const int q = c >> 4, s16 = c & 15;
    const bf16x8 vv = *(const bf16x8*)&bb[q * 128 + ((s16 ^ (q & 15)) << 3)];
    *(bf16x8*)(ob + (size_t)(b * S_ + q0 + q) * E_ + h * HD_ + s16 * 8) = vv;
  }
}

// ---------------- launcher ----------------
extern "C" void kernel_launch(void* const* d_in, const int* in_sizes, int n_in,
                              void* d_out, int out_size, void* d_ws, size_t ws_size,
                              hipStream_t stream) {
  const float* x   = (const float*)d_in[0];
  // d_in[1] = attn_mask: reference never applies it
  const float* wq  = (const float*)d_in[2];
  const float* bq  = (const float*)d_in[3];
  const float* wkv = (const float*)d_in[4];
  const float* bkv = (const float*)d_in[5];
  const float* wo  = (const float*)d_in[6];
  const float* wg  = (const float*)d_in[7];
  const float* wu  = (const float*)d_in[8];
  const float* wd  = (const float*)d_in[9];
  const float* n1  = (const float*)d_in[10];
  const float* n2  = (const float*)d_in[11];
  float* out = (float*)d_out;
  char* ws = (char*)d_ws;
  // Activations:
  bf16* y    = (bf16*)(ws);                   // 16 MiB [attn-out o; then y2]
  bf16* qkvb = (bf16*)(ws + (16ull << 20));   // 24 MiB fused q|k|v, row stride 3072
  bf16* x1   = (bf16*)(ws + (40ull << 20));   // 16 MiB (bf16 residual)
  bf16* gh   = (bf16*)(ws + (56ull << 20));   // 64 MiB (h); first 4 MiB aliased as vT pre-gu
  bf16* vT   = gh;                            // 4 MiB, dead once gu writes gh
  bf16* o    = y;
  bf16* y2   = y;
  // Tier A: bf16 weight mirrors, contiguous 116 MiB at +120
  bf16* wqkvb = (bf16*)(ws + (120ull << 20)); // 12 MiB: wq rows then wkv rows
  bf16* wob   = (bf16*)(ws + (132ull << 20)); // 8 MiB
  bf16* wgb   = (bf16*)(ws + (140ull << 20)); // 32 MiB
  bf16* wub   = (bf16*)(ws + (172ull << 20)); // 32 MiB
  bf16* wdb   = (bf16*)(ws + (204ull << 20)); // 32 MiB -> end 236 MiB
  const int M = B_ * S_;  // 4096
  const bool tierA = ws_size >= (236ull << 20);

  if (tierA)
    cvt6_k<<<2048, 256, 0, stream>>>(wq, wkv, wo, wg, wu, wd, wqkvb);

  rmsnorm_k<float><<<M, 256, 0, stream>>>(x, n1, y);
  if (tierA) {
    gemm_bt<0, true><<<dim3(QKS / 128, M / 128), 256, 0, stream>>>(
        y, wqkvb, bq, bkv, nullptr, qkvb, M, QKS, E_);
  } else {
    gemm_bt<0, false><<<dim3(E_ / 128, M / 128), 256, 0, stream>>>(
        y, wq, bq, nullptr, nullptr, qkvb, M, QKS, E_);
    gemm_bt<0, false><<<dim3(KVROW / 128, M / 128), 256, 0, stream>>>(
        y, wkv, bkv, nullptr, nullptr, qkvb + 2048, M, QKS, E_);
  }
  rope_k<<<(B_ * S_ * (H_ + KVH_) * 64) / 256, 256, 0, stream>>>(qkvb);
  vtrans_k<<<dim3(S_ / 64, KVH_, B_), 256, 0, stream>>>(qkvb, vT);
  attn_k<<<dim3(S_ / 128, H_, B_), 256, 0, stream>>>(qkvb, vT, o);
  if (tierA) {
    gemm_bt<1, true><<<dim3(E_ / 128, M / 128), 256, 0, stream>>>(
        o, wob, nullptr, nullptr, x, x1, M, E_, E_);
    rmsnorm_k<bf16><<<M, 256, 0, stream>>>(x1, n2, y2);
    gemm_gu<<<dim3(I_ / 128, M / 128), 256, 0, stream>>>(y2, wgb, wub, gh, M, I_, E_);
    gemm_bt<3, true><<<dim3(E_ / 128, M / 128), 256, 0, stream>>>(
        gh, wdb, nullptr, nullptr, x1, out, M, E_, I_);
  } else {
    gemm_bt<1, false><<<dim3(E_ / 128, M / 128), 256, 0, stream>>>(
        o, wo, nullptr, nullptr, x, x1, M, E_, E_);
    rmsnorm_k<bf16><<<M, 256, 0, stream>>>(x1, n2, y2);
    gemm_bt<0, false><<<dim3(I_ / 128, M / 128), 256, 0, stream>>>(
        y2, wg, nullptr, nullptr, nullptr, gh, M, I_, E_);
    gemm_bt<2, false><<<dim3(I_ / 128, M / 128), 256, 0, stream>>>(
        y2, wu, nullptr, nullptr, gh, gh, M, I_, E_);
    gemm_bt<3, false><<<dim3(E_ / 128, M / 128), 256, 0, stream>>>(
        gh, wd, nullptr, nullptr, x1, out, M, E_, I_);
  }
}

// Round 17
// 688.722 us; speedup vs baseline: 1.1620x; 1.0283x over previous
//
#include <hip/hip_runtime.h>

typedef __bf16 bf16;
typedef __bf16 bf16x8 __attribute__((ext_vector_type(8)));
typedef __bf16 bf16x4 __attribute__((ext_vector_type(4)));
typedef float f32x4 __attribute__((ext_vector_type(4)));

#define DEV __device__ __forceinline__

constexpr int B_ = 2, S_ = 2048, E_ = 2048, H_ = 16, KVH_ = 4, HD_ = 128, I_ = 8192;
constexpr int KVROW = 2 * KVH_ * HD_;   // 1024
constexpr int QKS = 3072;               // fused qkv row stride
constexpr float EPS_ = 1e-6f;
constexpr float SCALE_ = 0.08838834764831845f;  // 128^-0.5

DEV void gload_lds16(const bf16* g, bf16* l) {
  __builtin_amdgcn_global_load_lds(
      (const __attribute__((address_space(1))) void*)g,
      (__attribute__((address_space(3))) void*)l, 16, 0, 0);
}

// ---------------- fused f32 -> bf16 conversion of all 6 weights ----------------
__global__ __launch_bounds__(256) void cvt6_k(const float* __restrict__ s0, const float* __restrict__ s1,
                                              const float* __restrict__ s2, const float* __restrict__ s3,
                                              const float* __restrict__ s4, const float* __restrict__ s5,
                                              bf16* __restrict__ dst) {
  constexpr size_t N0 = 4194304, N1 = 2097152, N2 = 4194304,
                   N3 = 16777216, N4 = 16777216, N5 = 16777216;
  constexpr size_t TOT = N0 + N1 + N2 + N3 + N4 + N5;
  for (size_t i = ((size_t)blockIdx.x * 256 + threadIdx.x) * 8; i < TOT;
       i += (size_t)gridDim.x * 256 * 8) {
    size_t off = i; const float* sp;
    if (off < N0) sp = s0;
    else if ((off -= N0) < N1) sp = s1;
    else if ((off -= N1) < N2) sp = s2;
    else if ((off -= N2) < N3) sp = s3;
    else if ((off -= N3) < N4) sp = s4;
    else { off -= N4; sp = s5; }
    const float4* p = (const float4*)(sp + off);
    float4 a = p[0], b = p[1];
    bf16x8 o;
    o[0]=(bf16)a.x; o[1]=(bf16)a.y; o[2]=(bf16)a.z; o[3]=(bf16)a.w;
    o[4]=(bf16)b.x; o[5]=(bf16)b.y; o[6]=(bf16)b.z; o[7]=(bf16)b.w;
    *(bf16x8*)(dst + i) = o;
  }
}

// ---------------- RMSNorm: one block per row of E_=2048 -> bf16 out ----------------
template <typename InT>
__global__ __launch_bounds__(256) void rmsnorm_k(const InT* __restrict__ x,
                                                 const float* __restrict__ w,
                                                 bf16* __restrict__ y) {
  const int row = blockIdx.x, t = threadIdx.x;
  const size_t base = (size_t)row * E_ + t * 8;
  float v[8];
  if constexpr (sizeof(InT) == 2) {
    bf16x8 d = *(const bf16x8*)(x + base);
#pragma unroll
    for (int j = 0; j < 8; ++j) v[j] = (float)d[j];
  } else {
    const float4* p = (const float4*)(x + base);
    float4 a = p[0], b2 = p[1];
    v[0]=a.x; v[1]=a.y; v[2]=a.z; v[3]=a.w; v[4]=b2.x; v[5]=b2.y; v[6]=b2.z; v[7]=b2.w;
  }
  float ss = 0.f;
#pragma unroll
  for (int j = 0; j < 8; ++j) ss += v[j] * v[j];
#pragma unroll
  for (int off = 32; off; off >>= 1) ss += __shfl_xor(ss, off);
  __shared__ float red[4];
  if ((t & 63) == 0) red[t >> 6] = ss;
  __syncthreads();
  ss = red[0] + red[1] + red[2] + red[3];
  const float sc = rsqrtf(ss * (1.0f / E_) + EPS_);
  const float4* wp = (const float4*)(w + t * 8);
  float4 wa = wp[0], wb = wp[1];
  float wv[8] = {wa.x, wa.y, wa.z, wa.w, wb.x, wb.y, wb.z, wb.w};
  bf16x8 o;
#pragma unroll
  for (int j = 0; j < 8; ++j) o[j] = (bf16)(v[j] * sc * wv[j]);
  *(bf16x8*)(y + base) = o;
}

// ---------------- split-K reduce: out = p0 + p1 + x1 (f32 out) ----------------
__global__ __launch_bounds__(256) void red_k(const bf16* __restrict__ p0,
                                             const bf16* __restrict__ p1,
                                             const bf16* __restrict__ x1,
                                             float* __restrict__ out) {
  const size_t i = ((size_t)blockIdx.x * 256 + threadIdx.x) * 8;
  bf16x8 a = *(const bf16x8*)(p0 + i);
  bf16x8 b = *(const bf16x8*)(p1 + i);
  bf16x8 c = *(const bf16x8*)(x1 + i);
  float4 o0, o1;
  o0.x = (float)a[0] + (float)b[0] + (float)c[0];
  o0.y = (float)a[1] + (float)b[1] + (float)c[1];
  o0.z = (float)a[2] + (float)b[2] + (float)c[2];
  o0.w = (float)a[3] + (float)b[3] + (float)c[3];
  o1.x = (float)a[4] + (float)b[4] + (float)c[4];
  o1.y = (float)a[5] + (float)b[5] + (float)c[5];
  o1.z = (float)a[6] + (float)b[6] + (float)c[6];
  o1.w = (float)a[7] + (float)b[7] + (float)c[7];
  ((float4*)(out + i))[0] = o0;
  ((float4*)(out + i))[1] = o1;
}

// ---------------- RoPE in place on fused qkv buffer [M][3072] ----------------
__global__ __launch_bounds__(256) void rope_k(bf16* __restrict__ qkvb) {
  const int gid = blockIdx.x * 256 + threadIdx.x;   // B*S*(H+KV)*64 total
  const int d = gid & 63;
  const int r = gid >> 6;
  const int hh = r % (H_ + KVH_);
  const int s = (r / (H_ + KVH_)) % S_;
  const int b = r / ((H_ + KVH_) * S_);
  bf16* p = qkvb + (size_t)(b * S_ + s) * QKS +
            (hh < H_ ? hh * HD_ : 2048 + (hh - H_) * HD_);
  const float invf = exp2f(-(float)d * (13.287712379549449f / 64.f)); // 10000^(-d/64)
  float sn, cs;
  sincosf((float)s * invf, &sn, &cs);
  const float x1 = (float)p[d], x2 = (float)p[d + 64];
  p[d] = (bf16)(x1 * cs - x2 * sn);
  p[d + 64] = (bf16)(x2 * cs + x1 * sn);
}

// ---------------- V transpose: qkvb[..][2560+kvh*128+d] -> vT[b][kvh][d][s] ----------------
__global__ __launch_bounds__(256) void vtrans_k(const bf16* __restrict__ qkvb,
                                                bf16* __restrict__ vT) {
  __shared__ bf16 lds[64 * 136];
  const int t = threadIdx.x;
  const int s0 = blockIdx.x * 64, kvh = blockIdx.y, b = blockIdx.z;
#pragma unroll
  for (int i = 0; i < 4; ++i) {   // stage 64 s-rows x 128 d, coalesced
    const int c = t + i * 256;
    const int row = c >> 4, slot = c & 15;
    *(bf16x8*)&lds[row * 136 + slot * 8] =
        *(const bf16x8*)(qkvb + (size_t)(b * S_ + s0 + row) * QKS + 2560 + kvh * HD_ + slot * 8);
  }
  __syncthreads();
#pragma unroll
  for (int i = 0; i < 4; ++i) {   // write 128 d-rows x 64 s, coalesced
    const int c = t + i * 256;
    const int d = c >> 3, ss = c & 7;
    bf16x8 pk;
#pragma unroll
    for (int j = 0; j < 8; ++j) pk[j] = lds[(ss * 8 + j) * 136 + d];
    *(bf16x8*)(vT + (size_t)((b * KVH_ + kvh) * HD_ + d) * S_ + s0 + ss * 8) = pk;
  }
}

// ---------------- Fused gate+up GEMM (r11 proven): h = silu(A@Wg^T)*(A@Wu^T) --------
__global__ __launch_bounds__(256, 2) void gemm_gu(const bf16* __restrict__ A,
                                                  const bf16* __restrict__ Wg,
                                                  const bf16* __restrict__ Wu,
                                                  bf16* __restrict__ out,
                                                  int M, int N, int K) {
  constexpr int BK = 64;
  __shared__ bf16 As[128 * BK];
  __shared__ bf16 Bg[128 * BK];
  __shared__ bf16 Bu[128 * BK];
  const int t = threadIdx.x, lane = t & 63, w = t >> 6;
  const int g = lane >> 4, l15 = lane & 15;
  const int bm = blockIdx.y, bn = blockIdx.x;   // r11 orientation (measured best)
  const int wm = w >> 1, wn = w & 1;
  f32x4 ag[4][4], au[4][4];
#pragma unroll
  for (int i = 0; i < 4; ++i)
#pragma unroll
    for (int j = 0; j < 4; ++j) { ag[i][j] = {0.f,0.f,0.f,0.f}; au[i][j] = {0.f,0.f,0.f,0.f}; }

  const bf16* Ab  = A  + (size_t)bm * 128 * K;
  const bf16* Wgb = Wg + (size_t)bn * 128 * K;
  const bf16* Wub = Wu + (size_t)bn * 128 * K;

  for (int k0 = 0; k0 < K; k0 += BK) {
    __syncthreads();
#pragma unroll
    for (int i = 0; i < 4; ++i) {
      const int c = t + i * 256;
      const int row = c >> 3, slot = c & 7;
      const size_t goff = (size_t)row * K + k0 + ((slot ^ (row & 7)) << 3);
      gload_lds16(Ab + goff, &As[c * 8]);
      gload_lds16(Wgb + goff, &Bg[c * 8]);
      gload_lds16(Wub + goff, &Bu[c * 8]);
    }
    __syncthreads();
#pragma unroll
    for (int ks = 0; ks < 2; ++ks) {
      bf16x8 af[4], bgv[4], buv[4];
#pragma unroll
      for (int mt = 0; mt < 4; ++mt) {
        const int row = wm * 64 + mt * 16 + l15;
        af[mt] = *(const bf16x8*)&As[row * BK + (((ks * 4 + g) ^ (row & 7)) << 3)];
      }
#pragma unroll
      for (int nt = 0; nt < 4; ++nt) {
        const int row = wn * 64 + nt * 16 + l15;
        const int off = row * BK + (((ks * 4 + g) ^ (row & 7)) << 3);
        bgv[nt] = *(const bf16x8*)&Bg[off];
        buv[nt] = *(const bf16x8*)&Bu[off];
      }
#pragma unroll
      for (int mt = 0; mt < 4; ++mt)
#pragma unroll
        for (int nt = 0; nt < 4; ++nt) {
          ag[mt][nt] = __builtin_amdgcn_mfma_f32_16x16x32_bf16(af[mt], bgv[nt], ag[mt][nt], 0, 0, 0);
          au[mt][nt] = __builtin_amdgcn_mfma_f32_16x16x32_bf16(af[mt], buv[nt], au[mt][nt], 0, 0, 0);
        }
    }
  }

  const int row0 = bm * 128 + wm * 64;
  const int col0 = bn * 128 + wn * 64;
#pragma unroll
  for (int nt = 0; nt < 4; ++nt) {
    const int col = col0 + nt * 16 + l15;
#pragma unroll
    for (int mt = 0; mt < 4; ++mt) {
#pragma unroll
      for (int r = 0; r < 4; ++r) {
        const int rowi = row0 + mt * 16 + g * 4 + r;
        const float gv = ag[mt][nt][r];
        const float hv = (gv / (1.f + __expf(-gv))) * au[mt][nt][r];
        out[(size_t)rowi * N + col] = (bf16)hv;
      }
    }
  }
}

// ---------------- split-K down-proj: 128M x 256N tile, gu-ratio, bf16 partial --------
// grid (N/256, M/128, 2); z = K-half. Kt = total K (stride), each half does Kt/2.
__global__ __launch_bounds__(256, 2) void gemm_dn(const bf16* __restrict__ A,
                                                  const bf16* __restrict__ W,
                                                  bf16* __restrict__ part0,
                                                  bf16* __restrict__ part1,
                                                  int M, int N, int Kt) {
  constexpr int BK = 64;
  __shared__ bf16 As[128 * BK];
  __shared__ bf16 Bs[256 * BK];
  const int t = threadIdx.x, lane = t & 63, w = t >> 6;
  const int g = lane >> 4, l15 = lane & 15;
  const int bm = blockIdx.y, bn = blockIdx.x, z = blockIdx.z;
  const int wm = w >> 1, wn = w & 1;
  const int Koff = z * (Kt >> 1), Kend = Koff + (Kt >> 1);
  f32x4 acc[4][8];
#pragma unroll
  for (int i = 0; i < 4; ++i)
#pragma unroll
    for (int j = 0; j < 8; ++j) acc[i][j] = {0.f, 0.f, 0.f, 0.f};

  const bf16* Ab = A + (size_t)bm * 128 * Kt;
  const bf16* Wb = W + (size_t)bn * 256 * Kt;

  for (int k0 = Koff; k0 < Kend; k0 += BK) {
    __syncthreads();
#pragma unroll
    for (int i = 0; i < 4; ++i) {           // A: 128 rows
      const int c = t + i * 256;
      const int row = c >> 3, slot = c & 7;
      gload_lds16(Ab + (size_t)row * Kt + k0 + ((slot ^ (row & 7)) << 3), &As[c * 8]);
    }
#pragma unroll
    for (int i = 0; i < 8; ++i) {           // B: 256 rows
      const int c = t + i * 256;
      const int row = c >> 3, slot = c & 7;
      gload_lds16(Wb + (size_t)row * Kt + k0 + ((slot ^ (row & 7)) << 3), &Bs[c * 8]);
    }
    __syncthreads();
#pragma unroll
    for (int ks = 0; ks < 2; ++ks) {
      bf16x8 af[4], bfv[8];
#pragma unroll
      for (int mt = 0; mt < 4; ++mt) {
        const int row = wm * 64 + mt * 16 + l15;
        af[mt] = *(const bf16x8*)&As[row * BK + (((ks * 4 + g) ^ (row & 7)) << 3)];
      }
#pragma unroll
      for (int nt = 0; nt < 8; ++nt) {
        const int row = wn * 128 + nt * 16 + l15;
        bfv[nt] = *(const bf16x8*)&Bs[row * BK + (((ks * 4 + g) ^ (row & 7)) << 3)];
      }
#pragma unroll
      for (int mt = 0; mt < 4; ++mt)
#pragma unroll
        for (int nt = 0; nt < 8; ++nt)
          acc[mt][nt] = __builtin_amdgcn_mfma_f32_16x16x32_bf16(af[mt], bfv[nt], acc[mt][nt], 0, 0, 0);
    }
  }

  bf16* part = z ? part1 : part0;
  const int row0 = bm * 128 + wm * 64;
  const int col0 = bn * 256 + wn * 128;
#pragma unroll
  for (int nt = 0; nt < 8; ++nt) {
    const int col = col0 + nt * 16 + l15;
#pragma unroll
    for (int mt = 0; mt < 4; ++mt) {
#pragma unroll
      for (int r = 0; r < 4; ++r) {
        const int rowi = row0 + mt * 16 + g * 4 + r;
        part[(size_t)rowi * N + col] = (bf16)acc[mt][nt][r];
      }
    }
  }
}

// ---------------- GEMM 128x128 (m97 structure; proven config: >=512 blocks, 2/CU) ----
// EPI: 0 = (+dual bias) -> bf16; 1 = + f32 ext -> bf16; 2 = silu(bf16 ext)*acc -> bf16;
//      3 = + bf16 ext -> f32 out
template <int EPI, bool WB>
__global__ __launch_bounds__(256, 2) void gemm_bt(const bf16* __restrict__ A,
                                                  const void* __restrict__ Wp,
                                                  const float* __restrict__ bias0,
                                                  const float* __restrict__ bias1,
                                                  const void* __restrict__ ext,
                                                  void* __restrict__ out,
                                                  int M, int N, int K) {
  constexpr int BK = 64;
  __shared__ bf16 As[128 * BK];
  __shared__ bf16 Bs[128 * BK];
  const int t = threadIdx.x, lane = t & 63, w = t >> 6;
  const int g = lane >> 4, l15 = lane & 15;
  const int bm = blockIdx.y, bn = blockIdx.x;
  const int wm = w >> 1, wn = w & 1;
  f32x4 acc[4][4];
#pragma unroll
  for (int i = 0; i < 4; ++i)
#pragma unroll
    for (int j = 0; j < 4; ++j) acc[i][j] = {0.f, 0.f, 0.f, 0.f};

  const bf16* Ab = A + (size_t)bm * 128 * K;

  for (int k0 = 0; k0 < K; k0 += BK) {
    __syncthreads();
#pragma unroll
    for (int i = 0; i < 4; ++i) {
      const int c = t + i * 256;
      const int row = c >> 3, slot = c & 7;
      gload_lds16(Ab + (size_t)row * K + k0 + ((slot ^ (row & 7)) << 3), &As[c * 8]);
    }
    if constexpr (WB) {
      const bf16* Wb = (const bf16*)Wp + (size_t)bn * 128 * K;
#pragma unroll
      for (int i = 0; i < 4; ++i) {
        const int c = t + i * 256;
        const int row = c >> 3, slot = c & 7;
        gload_lds16(Wb + (size_t)row * K + k0 + ((slot ^ (row & 7)) << 3), &Bs[c * 8]);
      }
    } else {
      const float* Wb = (const float*)Wp + (size_t)bn * 128 * K;
#pragma unroll
      for (int i = 0; i < 4; ++i) {
        const int c = t + i * 256;
        const int row = c >> 3, slot = c & 7;
        const float4* wp = (const float4*)(Wb + (size_t)row * K + k0 + slot * 8);
        float4 w0 = wp[0], w1 = wp[1];
        bf16x8 pk;
        pk[0] = (bf16)w0.x; pk[1] = (bf16)w0.y; pk[2] = (bf16)w0.z; pk[3] = (bf16)w0.w;
        pk[4] = (bf16)w1.x; pk[5] = (bf16)w1.y; pk[6] = (bf16)w1.z; pk[7] = (bf16)w1.w;
        *(bf16x8*)&Bs[row * BK + ((slot ^ (row & 7)) << 3)] = pk;
      }
    }
    __syncthreads();
#pragma unroll
    for (int ks = 0; ks < 2; ++ks) {
      bf16x8 af[4], bfv[4];
#pragma unroll
      for (int mt = 0; mt < 4; ++mt) {
        const int row = wm * 64 + mt * 16 + l15;
        af[mt] = *(const bf16x8*)&As[row * BK + (((ks * 4 + g) ^ (row & 7)) << 3)];
      }
#pragma unroll
      for (int nt = 0; nt < 4; ++nt) {
        const int row = wn * 64 + nt * 16 + l15;
        bfv[nt] = *(const bf16x8*)&Bs[row * BK + (((ks * 4 + g) ^ (row & 7)) << 3)];
      }
#pragma unroll
      for (int mt = 0; mt < 4; ++mt)
#pragma unroll
        for (int nt = 0; nt < 4; ++nt)
          acc[mt][nt] = __builtin_amdgcn_mfma_f32_16x16x32_bf16(af[mt], bfv[nt], acc[mt][nt], 0, 0, 0);
    }
  }

  const int row0 = bm * 128 + wm * 64;
  const int col0 = bn * 128 + wn * 64;
#pragma unroll
  for (int nt = 0; nt < 4; ++nt) {
    const int col = col0 + nt * 16 + l15;
    float bv = 0.f;
    if constexpr (EPI == 0) {
      if (bias0) bv = (col < 2048 || !bias1) ? bias0[col] : bias1[col - 2048];
    }
#pragma unroll
    for (int mt = 0; mt < 4; ++mt) {
#pragma unroll
      for (int r = 0; r < 4; ++r) {
        const int rowi = row0 + mt * 16 + g * 4 + r;
        const size_t idx = (size_t)rowi * N + col;
        float v = acc[mt][nt][r] + bv;
        if constexpr (EPI == 0) {
          ((bf16*)out)[idx] = (bf16)v;
        } else if constexpr (EPI == 1) {
          v += ((const float*)ext)[idx];
          ((bf16*)out)[idx] = (bf16)v;
        } else if constexpr (EPI == 2) {
          const float gv = (float)((const bf16*)ext)[idx];
          const float sg = gv / (1.f + __expf(-gv));
          ((bf16*)out)[idx] = (bf16)(sg * v);
        } else {
          v += (float)((const bf16*)ext)[idx];
          ((float*)out)[idx] = v;
        }
      }
    }
  }
}

// ---------------- Flash attention (no mask, GQA 4:1); q/k from qkvb, V from vT ----------
__global__ __launch_bounds__(256, 2) void attn_k(const bf16* __restrict__ qkvb,
                                                 const bf16* __restrict__ vT,
                                                 bf16* __restrict__ ob) {
  __shared__ bf16 Ks[64 * 128];   // [kv][d], 256B rows, 16B-slot ^ (kv&15)
  __shared__ bf16 Vt[128 * 64];   // [d][kv], 128B rows, 16B-slot ^ (d&7)
  __shared__ bf16 Ps[4][32 * 64]; // per-wave [q][kv], slot ^ (q&7)
  const int t = threadIdx.x, lane = t & 63, w = t >> 6;
  const int g = lane >> 4, l15 = lane & 15;
  const int b = blockIdx.z, h = blockIdx.y;
  const int kvh = h >> 2;
  const int q0 = blockIdx.x * 128 + w * 32;
  const bf16* vTb = vT + (size_t)(b * KVH_ + kvh) * HD_ * S_;

  bf16x8 qf[2][4];  // B-frags: Q[q = qt*16+l15][d = ks*32+g*8 ..+7]
#pragma unroll
  for (int qt = 0; qt < 2; ++qt)
#pragma unroll
    for (int ks = 0; ks < 4; ++ks)
      qf[qt][ks] = *(const bf16x8*)(qkvb + (size_t)(b * S_ + q0 + qt * 16 + l15) * QKS + h * HD_ + ks * 32 + g * 8);

  f32x4 o[8][2];
#pragma unroll
  for (int i = 0; i < 8; ++i) { o[i][0] = {0.f,0.f,0.f,0.f}; o[i][1] = {0.f,0.f,0.f,0.f}; }
  float mA[2] = {-1e30f, -1e30f}, lA[2] = {0.f, 0.f};

  for (int s0 = 0; s0 < S_; s0 += 64) {
    __syncthreads();
#pragma unroll
    for (int i = 0; i < 4; ++i) {  // K tile via global_load_lds, source-swizzled
      const int c = t + i * 256;
      const int row = c >> 4, slot = c & 15;
      gload_lds16(qkvb + (size_t)(b * S_ + s0 + row) * QKS + 2048 + kvh * HD_ + ((slot ^ (row & 15)) << 3),
                  &Ks[c * 8]);
    }
#pragma unroll
    for (int i = 0; i < 4; ++i) {  // V^T tile via global_load_lds from vT, source-swizzled
      const int c = t + i * 256;
      const int row = c >> 3, slot = c & 7;   // row = d, 8 slots of 8 along s
      gload_lds16(vTb + (size_t)row * S_ + s0 + ((slot ^ (row & 7)) << 3), &Vt[c * 8]);
    }
    __syncthreads();

    f32x4 sc[2][4];
#pragma unroll
    for (int qt = 0; qt < 2; ++qt)
#pragma unroll
      for (int c = 0; c < 4; ++c) sc[qt][c] = {0.f,0.f,0.f,0.f};
    __builtin_amdgcn_s_setprio(1);
#pragma unroll
    for (int ks = 0; ks < 4; ++ks) {
      bf16x8 kf[4];
#pragma unroll
      for (int c = 0; c < 4; ++c) {
        const int kv = c * 16 + l15;
        kf[c] = *(const bf16x8*)&Ks[kv * 128 + (((ks * 4 + g) ^ (kv & 15)) << 3)];
      }
#pragma unroll
      for (int c = 0; c < 4; ++c) {
        sc[0][c] = __builtin_amdgcn_mfma_f32_16x16x32_bf16(kf[c], qf[0][ks], sc[0][c], 0, 0, 0);
        sc[1][c] = __builtin_amdgcn_mfma_f32_16x16x32_bf16(kf[c], qf[1][ks], sc[1][c], 0, 0, 0);
      }
    }
    __builtin_amdgcn_s_setprio(0);

    float corr[2];
#pragma unroll
    for (int qt = 0; qt < 2; ++qt) {   // lane-local online softmax (lane's q = qt*16+l15)
      float tm = sc[qt][0][0];
#pragma unroll
      for (int c = 0; c < 4; ++c)
#pragma unroll
        for (int r = 0; r < 4; ++r) tm = fmaxf(tm, sc[qt][c][r]);
      tm = fmaxf(tm, __shfl_xor(tm, 16));
      tm = fmaxf(tm, __shfl_xor(tm, 32));
      const float mn = fmaxf(mA[qt], tm);
      corr[qt] = __expf((mA[qt] - mn) * SCALE_);
      mA[qt] = mn;
      float ps = 0.f;
      const int q = qt * 16 + l15;
#pragma unroll
      for (int c = 0; c < 4; ++c)
#pragma unroll
        for (int r = 0; r < 4; ++r) {
          const float p = __expf((sc[qt][c][r] - mn) * SCALE_);
          ps += p;
          const int kv = c * 16 + g * 4 + r;
          Ps[w][q * 64 + (((kv >> 3) ^ (q & 7)) << 3) + (kv & 7)] = (bf16)p;
        }
      ps += __shfl_xor(ps, 16);
      ps += __shfl_xor(ps, 32);
      lA[qt] = lA[qt] * corr[qt] + ps;
#pragma unroll
      for (int dt = 0; dt < 8; ++dt) o[dt][qt] *= corr[qt];
    }
    asm volatile("s_waitcnt lgkmcnt(0)" ::: "memory");  // P round-trip fence (wave-private)
    __builtin_amdgcn_s_setprio(1);
#pragma unroll
    for (int ks = 0; ks < 2; ++ks) {
      bf16x8 pf[2];
#pragma unroll
      for (int qt = 0; qt < 2; ++qt) {
        const int q = qt * 16 + l15;
        pf[qt] = *(const bf16x8*)&Ps[w][q * 64 + (((ks * 4 + g) ^ (q & 7)) << 3)];
      }
#pragma unroll
      for (int dt = 0; dt < 8; ++dt) {
        const int d = dt * 16 + l15;
        const bf16x8 vf = *(const bf16x8*)&Vt[d * 64 + (((ks * 4 + g) ^ (d & 7)) << 3)];
        o[dt][0] = __builtin_amdgcn_mfma_f32_16x16x32_bf16(vf, pf[0], o[dt][0], 0, 0, 0);
        o[dt][1] = __builtin_amdgcn_mfma_f32_16x16x32_bf16(vf, pf[1], o[dt][1], 0, 0, 0);
      }
    }
    __builtin_amdgcn_s_setprio(0);
  }

  // normalize + coalesced store via per-wave LDS bounce (reuse Ks/Vt)
  const float inv0 = 1.f / lA[0], inv1 = 1.f / lA[1];
  __syncthreads();
  bf16* bb = (w < 2) ? &Ks[(w & 1) * 4096] : &Vt[(w & 1) * 4096];
#pragma unroll
  for (int dt = 0; dt < 8; ++dt)
#pragma unroll
    for (int qt = 0; qt < 2; ++qt) {
      const float iv = qt ? inv1 : inv0;
      bf16x4 pk;
#pragma unroll
      for (int r = 0; r < 4; ++r) pk[r] = (bf16)(o[dt][qt][r] * iv);
      const int q = qt * 16 + l15;
      const int s16 = (dt * 2 + (g >> 1)) ^ (q & 15);     // 16 slots per 256B row
      *(bf16x4*)&bb[q * 128 + (s16 << 3) + ((g & 1) << 2)] = pk;
    }
  asm volatile("s_waitcnt lgkmcnt(0)" ::: "memory");
#pragma unroll
  for (int it = 0; it < 8; ++it) {
    const int c = lane + it * 64;
    const int q = c >> 4, s16 = c & 15;
    const bf16x8 vv = *(const bf16x8*)&bb[q * 128 + ((s16 ^ (q & 15)) << 3)];
    *(bf16x8*)(ob + (size_t)(b * S_ + q0 + q) * E_ + h * HD_ + s16 * 8) = vv;
  }
}

// ---------------- launcher ----------------
extern "C" void kernel_launch(void* const* d_in, const int* in_sizes, int n_in,
                              void* d_out, int out_size, void* d_ws, size_t ws_size,
                              hipStream_t stream) {
  const float* x   = (const float*)d_in[0];
  // d_in[1] = attn_mask: reference never applies it
  const float* wq  = (const float*)d_in[2];
  const float* bq  = (const float*)d_in[3];
  const float* wkv = (const float*)d_in[4];
  const float* bkv = (const float*)d_in[5];
  const float* wo  = (const float*)d_in[6];
  const float* wg  = (const float*)d_in[7];
  const float* wu  = (const float*)d_in[8];
  const float* wd  = (const float*)d_in[9];
  const float* n1  = (const float*)d_in[10];
  const float* n2  = (const float*)d_in[11];
  float* out = (float*)d_out;
  char* ws = (char*)d_ws;
  // Activations:
  bf16* y    = (bf16*)(ws);                   // 16 MiB [attn-out o; then y2]; later part0
  bf16* qkvb = (bf16*)(ws + (16ull << 20));   // 24 MiB fused q|k|v; first 16 MiB later part1
  bf16* x1   = (bf16*)(ws + (40ull << 20));   // 16 MiB (bf16 residual)
  bf16* gh   = (bf16*)(ws + (56ull << 20));   // 64 MiB (h); first 4 MiB aliased as vT pre-gu
  bf16* vT   = gh;                            // 4 MiB, dead once gu writes gh
  bf16* o    = y;
  bf16* y2   = y;
  bf16* part0 = y;                            // dead after gu (y2 consumed)
  bf16* part1 = qkvb;                         // dead after attn
  // Tier A: bf16 weight mirrors, contiguous 116 MiB at +120
  bf16* wqkvb = (bf16*)(ws + (120ull << 20)); // 12 MiB: wq rows then wkv rows
  bf16* wob   = (bf16*)(ws + (132ull << 20)); // 8 MiB
  bf16* wgb   = (bf16*)(ws + (140ull << 20)); // 32 MiB
  bf16* wub   = (bf16*)(ws + (172ull << 20)); // 32 MiB
  bf16* wdb   = (bf16*)(ws + (204ull << 20)); // 32 MiB -> end 236 MiB
  const int M = B_ * S_;  // 4096
  const bool tierA = ws_size >= (236ull << 20);

  if (tierA)
    cvt6_k<<<2048, 256, 0, stream>>>(wq, wkv, wo, wg, wu, wd, wqkvb);

  rmsnorm_k<float><<<M, 256, 0, stream>>>(x, n1, y);
  if (tierA) {
    gemm_bt<0, true><<<dim3(QKS / 128, M / 128), 256, 0, stream>>>(
        y, wqkvb, bq, bkv, nullptr, qkvb, M, QKS, E_);
  } else {
    gemm_bt<0, false><<<dim3(E_ / 128, M / 128), 256, 0, stream>>>(
        y, wq, bq, nullptr, nullptr, qkvb, M, QKS, E_);
    gemm_bt<0, false><<<dim3(KVROW / 128, M / 128), 256, 0, stream>>>(
        y, wkv, bkv, nullptr, nullptr, qkvb + 2048, M, QKS, E_);
  }
  rope_k<<<(B_ * S_ * (H_ + KVH_) * 64) / 256, 256, 0, stream>>>(qkvb);
  vtrans_k<<<dim3(S_ / 64, KVH_, B_), 256, 0, stream>>>(qkvb, vT);
  attn_k<<<dim3(S_ / 128, H_, B_), 256, 0, stream>>>(qkvb, vT, o);
  if (tierA) {
    gemm_bt<1, true><<<dim3(E_ / 128, M / 128), 256, 0, stream>>>(
        o, wob, nullptr, nullptr, x, x1, M, E_, E_);
    rmsnorm_k<bf16><<<M, 256, 0, stream>>>(x1, n2, y2);
    gemm_gu<<<dim3(I_ / 128, M / 128), 256, 0, stream>>>(y2, wgb, wub, gh, M, I_, E_);
    gemm_dn<<<dim3(E_ / 256, M / 128, 2), 256, 0, stream>>>(gh, wdb, part0, part1, M, E_, I_);
    red_k<<<(M * E_) / (256 * 8), 256, 0, stream>>>(part0, part1, x1, out);
  } else {
    gemm_bt<1, false><<<dim3(E_ / 128, M / 128), 256, 0, stream>>>(
        o, wo, nullptr, nullptr, x, x1, M, E_, E_);
    rmsnorm_k<bf16><<<M, 256, 0, stream>>>(x1, n2, y2);
    gemm_bt<0, false><<<dim3(I_ / 128, M / 128), 256, 0, stream>>>(
        y2, wg, nullptr, nullptr, nullptr, gh, M, I_, E_);
    gemm_bt<2, false><<<dim3(I_ / 128, M / 128), 256, 0, stream>>>(
        y2, wu, nullptr, nullptr, gh, gh, M, I_, E_);
    gemm_bt<3, false><<<dim3(E_ / 128, M / 128), 256, 0, stream>>>(
        gh, wd, nullptr, nullptr, x1, out, M, E_, I_);
  }
}

// Round 19
// 686.409 us; speedup vs baseline: 1.1660x; 1.0034x over previous
//
#include <hip/hip_runtime.h>

typedef __bf16 bf16;
typedef __bf16 bf16x8 __attribute__((ext_vector_type(8)));
typedef __bf16 bf16x4 __attribute__((ext_vector_type(4)));
typedef float f32x4 __attribute__((ext_vector_type(4)));

#define DEV __device__ __forceinline__

constexpr int B_ = 2, S_ = 2048, E_ = 2048, H_ = 16, KVH_ = 4, HD_ = 128, I_ = 8192;
constexpr int KVROW = 2 * KVH_ * HD_;   // 1024
constexpr int QKS = 3072;               // fused qkv row stride
constexpr float EPS_ = 1e-6f;
constexpr float SCALE_ = 0.08838834764831845f;  // 128^-0.5

DEV void gload_lds16(const bf16* g, bf16* l) {
  __builtin_amdgcn_global_load_lds(
      (const __attribute__((address_space(1))) void*)g,
      (__attribute__((address_space(3))) void*)l, 16, 0, 0);
}

// ---------------- fused f32 -> bf16 conversion of all 6 weights ----------------
__global__ __launch_bounds__(256) void cvt6_k(const float* __restrict__ s0, const float* __restrict__ s1,
                                              const float* __restrict__ s2, const float* __restrict__ s3,
                                              const float* __restrict__ s4, const float* __restrict__ s5,
                                              bf16* __restrict__ dst) {
  constexpr size_t N0 = 4194304, N1 = 2097152, N2 = 4194304,
                   N3 = 16777216, N4 = 16777216, N5 = 16777216;
  constexpr size_t TOT = N0 + N1 + N2 + N3 + N4 + N5;
  for (size_t i = ((size_t)blockIdx.x * 256 + threadIdx.x) * 8; i < TOT;
       i += (size_t)gridDim.x * 256 * 8) {
    size_t off = i; const float* sp;
    if (off < N0) sp = s0;
    else if ((off -= N0) < N1) sp = s1;
    else if ((off -= N1) < N2) sp = s2;
    else if ((off -= N2) < N3) sp = s3;
    else if ((off -= N3) < N4) sp = s4;
    else { off -= N4; sp = s5; }
    const float4* p = (const float4*)(sp + off);
    float4 a = p[0], b = p[1];
    bf16x8 o;
    o[0]=(bf16)a.x; o[1]=(bf16)a.y; o[2]=(bf16)a.z; o[3]=(bf16)a.w;
    o[4]=(bf16)b.x; o[5]=(bf16)b.y; o[6]=(bf16)b.z; o[7]=(bf16)b.w;
    *(bf16x8*)(dst + i) = o;
  }
}

// ---------------- RMSNorm: one block per row of E_=2048 -> bf16 out ----------------
template <typename InT>
__global__ __launch_bounds__(256) void rmsnorm_k(const InT* __restrict__ x,
                                                 const float* __restrict__ w,
                                                 bf16* __restrict__ y) {
  const int row = blockIdx.x, t = threadIdx.x;
  const size_t base = (size_t)row * E_ + t * 8;
  float v[8];
  if constexpr (sizeof(InT) == 2) {
    bf16x8 d = *(const bf16x8*)(x + base);
#pragma unroll
    for (int j = 0; j < 8; ++j) v[j] = (float)d[j];
  } else {
    const float4* p = (const float4*)(x + base);
    float4 a = p[0], b2 = p[1];
    v[0]=a.x; v[1]=a.y; v[2]=a.z; v[3]=a.w; v[4]=b2.x; v[5]=b2.y; v[6]=b2.z; v[7]=b2.w;
  }
  float ss = 0.f;
#pragma unroll
  for (int j = 0; j < 8; ++j) ss += v[j] * v[j];
#pragma unroll
  for (int off = 32; off; off >>= 1) ss += __shfl_xor(ss, off);
  __shared__ float red[4];
  if ((t & 63) == 0) red[t >> 6] = ss;
  __syncthreads();
  ss = red[0] + red[1] + red[2] + red[3];
  const float sc = rsqrtf(ss * (1.0f / E_) + EPS_);
  const float4* wp = (const float4*)(w + t * 8);
  float4 wa = wp[0], wb = wp[1];
  float wv[8] = {wa.x, wa.y, wa.z, wa.w, wb.x, wb.y, wb.z, wb.w};
  bf16x8 o;
#pragma unroll
  for (int j = 0; j < 8; ++j) o[j] = (bf16)(v[j] * sc * wv[j]);
  *(bf16x8*)(y + base) = o;
}

// ---------------- split-K reduce: out = p0 + p1 + x1 (f32 out) ----------------
__global__ __launch_bounds__(256) void red_k(const bf16* __restrict__ p0,
                                             const bf16* __restrict__ p1,
                                             const bf16* __restrict__ x1,
                                             float* __restrict__ out) {
  const size_t i = ((size_t)blockIdx.x * 256 + threadIdx.x) * 8;
  bf16x8 a = *(const bf16x8*)(p0 + i);
  bf16x8 b = *(const bf16x8*)(p1 + i);
  bf16x8 c = *(const bf16x8*)(x1 + i);
#pragma unroll
  for (int j = 0; j < 8; ++j)
    out[i + j] = (float)a[j] + (float)b[j] + (float)c[j];
}

// ---------------- RoPE in place on fused qkv buffer [M][3072] ----------------
__global__ __launch_bounds__(256) void rope_k(bf16* __restrict__ qkvb) {
  const int gid = blockIdx.x * 256 + threadIdx.x;   // B*S*(H+KV)*64 total
  const int d = gid & 63;
  const int r = gid >> 6;
  const int hh = r % (H_ + KVH_);
  const int s = (r / (H_ + KVH_)) % S_;
  const int b = r / ((H_ + KVH_) * S_);
  bf16* p = qkvb + (size_t)(b * S_ + s) * QKS +
            (hh < H_ ? hh * HD_ : 2048 + (hh - H_) * HD_);
  const float invf = exp2f(-(float)d * (13.287712379549449f / 64.f)); // 10000^(-d/64)
  float sn, cs;
  sincosf((float)s * invf, &sn, &cs);
  const float x1 = (float)p[d], x2 = (float)p[d + 64];
  p[d] = (bf16)(x1 * cs - x2 * sn);
  p[d + 64] = (bf16)(x2 * cs + x1 * sn);
}

// ---------------- V transpose: qkvb[..][2560+kvh*128+d] -> vT[b][kvh][d][s] ----------------
__global__ __launch_bounds__(256) void vtrans_k(const bf16* __restrict__ qkvb,
                                                bf16* __restrict__ vT) {
  __shared__ bf16 lds[64 * 136];
  const int t = threadIdx.x;
  const int s0 = blockIdx.x * 64, kvh = blockIdx.y, b = blockIdx.z;
#pragma unroll
  for (int i = 0; i < 4; ++i) {   // stage 64 s-rows x 128 d, coalesced
    const int c = t + i * 256;
    const int row = c >> 4, slot = c & 15;
    *(bf16x8*)&lds[row * 136 + slot * 8] =
        *(const bf16x8*)(qkvb + (size_t)(b * S_ + s0 + row) * QKS + 2560 + kvh * HD_ + slot * 8);
  }
  __syncthreads();
#pragma unroll
  for (int i = 0; i < 4; ++i) {   // write 128 d-rows x 64 s, coalesced
    const int c = t + i * 256;
    const int d = c >> 3, ss = c & 7;
    bf16x8 pk;
#pragma unroll
    for (int j = 0; j < 8; ++j) pk[j] = lds[(ss * 8 + j) * 136 + d];
    *(bf16x8*)(vT + (size_t)((b * KVH_ + kvh) * HD_ + d) * S_ + s0 + ss * 8) = pk;
  }
}

// ---------------- Fused gate+up GEMM (r11 proven): h = silu(A@Wg^T)*(A@Wu^T) --------
__global__ __launch_bounds__(256, 2) void gemm_gu(const bf16* __restrict__ A,
                                                  const bf16* __restrict__ Wg,
                                                  const bf16* __restrict__ Wu,
                                                  bf16* __restrict__ out,
                                                  int M, int N, int K) {
  constexpr int BK = 64;
  __shared__ bf16 As[128 * BK];
  __shared__ bf16 Bg[128 * BK];
  __shared__ bf16 Bu[128 * BK];
  const int t = threadIdx.x, lane = t & 63, w = t >> 6;
  const int g = lane >> 4, l15 = lane & 15;
  const int bm = blockIdx.y, bn = blockIdx.x;   // r11 orientation (measured best)
  const int wm = w >> 1, wn = w & 1;
  f32x4 ag[4][4], au[4][4];
#pragma unroll
  for (int i = 0; i < 4; ++i)
#pragma unroll
    for (int j = 0; j < 4; ++j) { ag[i][j] = {0.f,0.f,0.f,0.f}; au[i][j] = {0.f,0.f,0.f,0.f}; }

  const bf16* Ab  = A  + (size_t)bm * 128 * K;
  const bf16* Wgb = Wg + (size_t)bn * 128 * K;
  const bf16* Wub = Wu + (size_t)bn * 128 * K;

  for (int k0 = 0; k0 < K; k0 += BK) {
    __syncthreads();
#pragma unroll
    for (int i = 0; i < 4; ++i) {
      const int c = t + i * 256;
      const int row = c >> 3, slot = c & 7;
      const size_t goff = (size_t)row * K + k0 + ((slot ^ (row & 7)) << 3);
      gload_lds16(Ab + goff, &As[c * 8]);
      gload_lds16(Wgb + goff, &Bg[c * 8]);
      gload_lds16(Wub + goff, &Bu[c * 8]);
    }
    __syncthreads();
#pragma unroll
    for (int ks = 0; ks < 2; ++ks) {
      bf16x8 af[4], bgv[4], buv[4];
#pragma unroll
      for (int mt = 0; mt < 4; ++mt) {
        const int row = wm * 64 + mt * 16 + l15;
        af[mt] = *(const bf16x8*)&As[row * BK + (((ks * 4 + g) ^ (row & 7)) << 3)];
      }
#pragma unroll
      for (int nt = 0; nt < 4; ++nt) {
        const int row = wn * 64 + nt * 16 + l15;
        const int off = row * BK + (((ks * 4 + g) ^ (row & 7)) << 3);
        bgv[nt] = *(const bf16x8*)&Bg[off];
        buv[nt] = *(const bf16x8*)&Bu[off];
      }
#pragma unroll
      for (int mt = 0; mt < 4; ++mt)
#pragma unroll
        for (int nt = 0; nt < 4; ++nt) {
          ag[mt][nt] = __builtin_amdgcn_mfma_f32_16x16x32_bf16(af[mt], bgv[nt], ag[mt][nt], 0, 0, 0);
          au[mt][nt] = __builtin_amdgcn_mfma_f32_16x16x32_bf16(af[mt], buv[nt], au[mt][nt], 0, 0, 0);
        }
    }
  }

  const int row0 = bm * 128 + wm * 64;
  const int col0 = bn * 128 + wn * 64;
#pragma unroll
  for (int nt = 0; nt < 4; ++nt) {
    const int col = col0 + nt * 16 + l15;
#pragma unroll
    for (int mt = 0; mt < 4; ++mt) {
#pragma unroll
      for (int r = 0; r < 4; ++r) {
        const int rowi = row0 + mt * 16 + g * 4 + r;
        const float gv = ag[mt][nt][r];
        const float hv = (gv / (1.f + __expf(-gv))) * au[mt][nt][r];
        out[(size_t)rowi * N + col] = (bf16)hv;
      }
    }
  }
}

// ---------------- split-K down-proj: 128M x 256N tile, gu-ratio, bf16 partial --------
// grid (N/256, M/128, 2); z = K-half. Kt = total K (stride), each half does Kt/2.
__global__ __launch_bounds__(256, 2) void gemm_dn(const bf16* __restrict__ A,
                                                  const bf16* __restrict__ W,
                                                  bf16* __restrict__ part0,
                                                  bf16* __restrict__ part1,
                                                  int M, int N, int Kt) {
  constexpr int BK = 64;
  __shared__ bf16 As[128 * BK];
  __shared__ bf16 Bs[256 * BK];
  const int t = threadIdx.x, lane = t & 63, w = t >> 6;
  const int g = lane >> 4, l15 = lane & 15;
  const int bm = blockIdx.y, bn = blockIdx.x, z = blockIdx.z;
  const int wm = w >> 1, wn = w & 1;
  const int Koff = z * (Kt >> 1), Kend = Koff + (Kt >> 1);
  f32x4 acc[4][8];
#pragma unroll
  for (int i = 0; i < 4; ++i)
#pragma unroll
    for (int j = 0; j < 8; ++j) acc[i][j] = {0.f, 0.f, 0.f, 0.f};

  const bf16* Ab = A + (size_t)bm * 128 * Kt;
  const bf16* Wb = W + (size_t)bn * 256 * Kt;

  for (int k0 = Koff; k0 < Kend; k0 += BK) {
    __syncthreads();
#pragma unroll
    for (int i = 0; i < 4; ++i) {           // A: 128 rows
      const int c = t + i * 256;
      const int row = c >> 3, slot = c & 7;
      gload_lds16(Ab + (size_t)row * Kt + k0 + ((slot ^ (row & 7)) << 3), &As[c * 8]);
    }
#pragma unroll
    for (int i = 0; i < 8; ++i) {           // B: 256 rows
      const int c = t + i * 256;
      const int row = c >> 3, slot = c & 7;
      gload_lds16(Wb + (size_t)row * Kt + k0 + ((slot ^ (row & 7)) << 3), &Bs[c * 8]);
    }
    __syncthreads();
#pragma unroll
    for (int ks = 0; ks < 2; ++ks) {
      bf16x8 af[4], bfv[8];
#pragma unroll
      for (int mt = 0; mt < 4; ++mt) {
        const int row = wm * 64 + mt * 16 + l15;
        af[mt] = *(const bf16x8*)&As[row * BK + (((ks * 4 + g) ^ (row & 7)) << 3)];
      }
#pragma unroll
      for (int nt = 0; nt < 8; ++nt) {
        const int row = wn * 128 + nt * 16 + l15;
        bfv[nt] = *(const bf16x8*)&Bs[row * BK + (((ks * 4 + g) ^ (row & 7)) << 3)];
      }
#pragma unroll
      for (int mt = 0; mt < 4; ++mt)
#pragma unroll
        for (int nt = 0; nt < 8; ++nt)
          acc[mt][nt] = __builtin_amdgcn_mfma_f32_16x16x32_bf16(af[mt], bfv[nt], acc[mt][nt], 0, 0, 0);
    }
  }

  bf16* part = z ? part1 : part0;
  const int row0 = bm * 128 + wm * 64;
  const int col0 = bn * 256 + wn * 128;
#pragma unroll
  for (int nt = 0; nt < 8; ++nt) {
    const int col = col0 + nt * 16 + l15;
#pragma unroll
    for (int mt = 0; mt < 4; ++mt) {
#pragma unroll
      for (int r = 0; r < 4; ++r) {
        const int rowi = row0 + mt * 16 + g * 4 + r;
        part[(size_t)rowi * N + col] = (bf16)acc[mt][nt][r];
      }
    }
  }
}

// ---------------- GEMM 128x128 (m97 structure; proven config: >=512 blocks, 2/CU) ----
// EPI: 0 = (+dual bias) -> bf16; 1 = + f32 ext -> bf16; 2 = silu(bf16 ext)*acc -> bf16;
//      3 = + bf16 ext -> f32 out
template <int EPI, bool WB>
__global__ __launch_bounds__(256, 2) void gemm_bt(const bf16* __restrict__ A,
                                                  const void* __restrict__ Wp,
                                                  const float* __restrict__ bias0,
                                                  const float* __restrict__ bias1,
                                                  const void* __restrict__ ext,
                                                  void* __restrict__ out,
                                                  int M, int N, int K) {
  constexpr int BK = 64;
  __shared__ bf16 As[128 * BK];
  __shared__ bf16 Bs[128 * BK];
  const int t = threadIdx.x, lane = t & 63, w = t >> 6;
  const int g = lane >> 4, l15 = lane & 15;
  const int bm = blockIdx.y, bn = blockIdx.x;
  const int wm = w >> 1, wn = w & 1;
  f32x4 acc[4][4];
#pragma unroll
  for (int i = 0; i < 4; ++i)
#pragma unroll
    for (int j = 0; j < 4; ++j) acc[i][j] = {0.f, 0.f, 0.f, 0.f};

  const bf16* Ab = A + (size_t)bm * 128 * K;

  for (int k0 = 0; k0 < K; k0 += BK) {
    __syncthreads();
#pragma unroll
    for (int i = 0; i < 4; ++i) {
      const int c = t + i * 256;
      const int row = c >> 3, slot = c & 7;
      gload_lds16(Ab + (size_t)row * K + k0 + ((slot ^ (row & 7)) << 3), &As[c * 8]);
    }
    if constexpr (WB) {
      const bf16* Wb = (const bf16*)Wp + (size_t)bn * 128 * K;
#pragma unroll
      for (int i = 0; i < 4; ++i) {
        const int c = t + i * 256;
        const int row = c >> 3, slot = c & 7;
        gload_lds16(Wb + (size_t)row * K + k0 + ((slot ^ (row & 7)) << 3), &Bs[c * 8]);
      }
    } else {
      const float* Wb = (const float*)Wp + (size_t)bn * 128 * K;
#pragma unroll
      for (int i = 0; i < 4; ++i) {
        const int c = t + i * 256;
        const int row = c >> 3, slot = c & 7;
        const float4* wp = (const float4*)(Wb + (size_t)row * K + k0 + slot * 8);
        float4 w0 = wp[0], w1 = wp[1];
        bf16x8 pk;
        pk[0] = (bf16)w0.x; pk[1] = (bf16)w0.y; pk[2] = (bf16)w0.z; pk[3] = (bf16)w0.w;
        pk[4] = (bf16)w1.x; pk[5] = (bf16)w1.y; pk[6] = (bf16)w1.z; pk[7] = (bf16)w1.w;
        *(bf16x8*)&Bs[row * BK + ((slot ^ (row & 7)) << 3)] = pk;
      }
    }
    __syncthreads();
#pragma unroll
    for (int ks = 0; ks < 2; ++ks) {
      bf16x8 af[4], bfv[4];
#pragma unroll
      for (int mt = 0; mt < 4; ++mt) {
        const int row = wm * 64 + mt * 16 + l15;
        af[mt] = *(const bf16x8*)&As[row * BK + (((ks * 4 + g) ^ (row & 7)) << 3)];
      }
#pragma unroll
      for (int nt = 0; nt < 4; ++nt) {
        const int row = wn * 64 + nt * 16 + l15;
        bfv[nt] = *(const bf16x8*)&Bs[row * BK + (((ks * 4 + g) ^ (row & 7)) << 3)];
      }
#pragma unroll
      for (int mt = 0; mt < 4; ++mt)
#pragma unroll
        for (int nt = 0; nt < 4; ++nt)
          acc[mt][nt] = __builtin_amdgcn_mfma_f32_16x16x32_bf16(af[mt], bfv[nt], acc[mt][nt], 0, 0, 0);
    }
  }

  const int row0 = bm * 128 + wm * 64;
  const int col0 = bn * 128 + wn * 64;
#pragma unroll
  for (int nt = 0; nt < 4; ++nt) {
    const int col = col0 + nt * 16 + l15;
    float bv = 0.f;
    if constexpr (EPI == 0) {
      if (bias0) bv = (col < 2048 || !bias1) ? bias0[col] : bias1[col - 2048];
    }
#pragma unroll
    for (int mt = 0; mt < 4; ++mt) {
#pragma unroll
      for (int r = 0; r < 4; ++r) {
        const int rowi = row0 + mt * 16 + g * 4 + r;
        const size_t idx = (size_t)rowi * N + col;
        float v = acc[mt][nt][r] + bv;
        if constexpr (EPI == 0) {
          ((bf16*)out)[idx] = (bf16)v;
        } else if constexpr (EPI == 1) {
          v += ((const float*)ext)[idx];
          ((bf16*)out)[idx] = (bf16)v;
        } else if constexpr (EPI == 2) {
          const float gv = (float)((const bf16*)ext)[idx];
          const float sg = gv / (1.f + __expf(-gv));
          ((bf16*)out)[idx] = (bf16)(sg * v);
        } else {
          v += (float)((const bf16*)ext)[idx];
          ((float*)out)[idx] = v;
        }
      }
    }
  }
}

// ---------------- Flash attention (no mask, GQA 4:1); q/k from qkvb, V from vT ----------
__global__ __launch_bounds__(256, 2) void attn_k(const bf16* __restrict__ qkvb,
                                                 const bf16* __restrict__ vT,
                                                 bf16* __restrict__ ob) {
  __shared__ bf16 Ks[64 * 128];   // [kv][d], 256B rows, 16B-slot ^ (kv&15)
  __shared__ bf16 Vt[128 * 64];   // [d][kv], 128B rows, 16B-slot ^ (d&7)
  __shared__ bf16 Ps[4][32 * 64]; // per-wave [q][kv], slot ^ (q&7)
  const int t = threadIdx.x, lane = t & 63, w = t >> 6;
  const int g = lane >> 4, l15 = lane & 15;
  const int b = blockIdx.z, h = blockIdx.y;
  const int kvh = h >> 2;
  const int q0 = blockIdx.x * 128 + w * 32;
  const bf16* vTb = vT + (size_t)(b * KVH_ + kvh) * HD_ * S_;

  bf16x8 qf[2][4];  // B-frags: Q[q = qt*16+l15][d = ks*32+g*8 ..+7]
#pragma unroll
  for (int qt = 0; qt < 2; ++qt)
#pragma unroll
    for (int ks = 0; ks < 4; ++ks)
      qf[qt][ks] = *(const bf16x8*)(qkvb + (size_t)(b * S_ + q0 + qt * 16 + l15) * QKS + h * HD_ + ks * 32 + g * 8);

  f32x4 o[8][2];
#pragma unroll
  for (int i = 0; i < 8; ++i) { o[i][0] = {0.f,0.f,0.f,0.f}; o[i][1] = {0.f,0.f,0.f,0.f}; }
  float mA[2] = {-1e30f, -1e30f}, lA[2] = {0.f, 0.f};

  for (int s0 = 0; s0 < S_; s0 += 64) {
    __syncthreads();
#pragma unroll
    for (int i = 0; i < 4; ++i) {  // K tile via global_load_lds, source-swizzled
      const int c = t + i * 256;
      const int row = c >> 4, slot = c & 15;
      gload_lds16(qkvb + (size_t)(b * S_ + s0 + row) * QKS + 2048 + kvh * HD_ + ((slot ^ (row & 15)) << 3),
                  &Ks[c * 8]);
    }
#pragma unroll
    for (int i = 0; i < 4; ++i) {  // V^T tile via global_load_lds from vT, source-swizzled
      const int c = t + i * 256;
      const int row = c >> 3, slot = c & 7;   // row = d, 8 slots of 8 along s
      gload_lds16(vTb + (size_t)row * S_ + s0 + ((slot ^ (row & 7)) << 3), &Vt[c * 8]);
    }
    __syncthreads();

    f32x4 sc[2][4];
#pragma unroll
    for (int qt = 0; qt < 2; ++qt)
#pragma unroll
      for (int c = 0; c < 4; ++c) sc[qt][c] = {0.f,0.f,0.f,0.f};
    __builtin_amdgcn_s_setprio(1);
#pragma unroll
    for (int ks = 0; ks < 4; ++ks) {
      bf16x8 kf[4];
#pragma unroll
      for (int c = 0; c < 4; ++c) {
        const int kv = c * 16 + l15;
        kf[c] = *(const bf16x8*)&Ks[kv * 128 + (((ks * 4 + g) ^ (kv & 15)) << 3)];
      }
#pragma unroll
      for (int c = 0; c < 4; ++c) {
        sc[0][c] = __builtin_amdgcn_mfma_f32_16x16x32_bf16(kf[c], qf[0][ks], sc[0][c], 0, 0, 0);
        sc[1][c] = __builtin_amdgcn_mfma_f32_16x16x32_bf16(kf[c], qf[1][ks], sc[1][c], 0, 0, 0);
      }
    }
    __builtin_amdgcn_s_setprio(0);

    float corr[2];
#pragma unroll
    for (int qt = 0; qt < 2; ++qt) {   // lane-local online softmax (lane's q = qt*16+l15)
      float tm = sc[qt][0][0];
#pragma unroll
      for (int c = 0; c < 4; ++c)
#pragma unroll
        for (int r = 0; r < 4; ++r) tm = fmaxf(tm, sc[qt][c][r]);
      tm = fmaxf(tm, __shfl_xor(tm, 16));
      tm = fmaxf(tm, __shfl_xor(tm, 32));
      const float mn = fmaxf(mA[qt], tm);
      corr[qt] = __expf((mA[qt] - mn) * SCALE_);
      mA[qt] = mn;
      float ps = 0.f;
      const int q = qt * 16 + l15;
#pragma unroll
      for (int c = 0; c < 4; ++c)
#pragma unroll
        for (int r = 0; r < 4; ++r) {
          const float p = __expf((sc[qt][c][r] - mn) * SCALE_);
          ps += p;
          const int kv = c * 16 + g * 4 + r;
          Ps[w][q * 64 + (((kv >> 3) ^ (q & 7)) << 3) + (kv & 7)] = (bf16)p;
        }
      ps += __shfl_xor(ps, 16);
      ps += __shfl_xor(ps, 32);
      lA[qt] = lA[qt] * corr[qt] + ps;
#pragma unroll
      for (int dt = 0; dt < 8; ++dt) o[dt][qt] *= corr[qt];
    }
    asm volatile("s_waitcnt lgkmcnt(0)" ::: "memory");  // P round-trip fence (wave-private)
    __builtin_amdgcn_s_setprio(1);
#pragma unroll
    for (int ks = 0; ks < 2; ++ks) {
      bf16x8 pf[2];
#pragma unroll
      for (int qt = 0; qt < 2; ++qt) {
        const int q = qt * 16 + l15;
        pf[qt] = *(const bf16x8*)&Ps[w][q * 64 + (((ks * 4 + g) ^ (q & 7)) << 3)];
      }
#pragma unroll
      for (int dt = 0; dt < 8; ++dt) {
        const int d = dt * 16 + l15;
        const bf16x8 vf = *(const bf16x8*)&Vt[d * 64 + (((ks * 4 + g) ^ (d & 7)) << 3)];
        o[dt][0] = __builtin_amdgcn_mfma_f32_16x16x32_bf16(vf, pf[0], o[dt][0], 0, 0, 0);
        o[dt][1] = __builtin_amdgcn_mfma_f32_16x16x32_bf16(vf, pf[1], o[dt][1], 0, 0, 0);
      }
    }
    __builtin_amdgcn_s_setprio(0);
  }

  // normalize + coalesced store via per-wave LDS bounce (reuse Ks/Vt)
  const float inv0 = 1.f / lA[0], inv1 = 1.f / lA[1];
  __syncthreads();
  bf16* bb = (w < 2) ? &Ks[(w & 1) * 4096] : &Vt[(w & 1) * 4096];
#pragma unroll
  for (int dt = 0; dt < 8; ++dt)
#pragma unroll
    for (int qt = 0; qt < 2; ++qt) {
      const float iv = qt ? inv1 : inv0;
      bf16x4 pk;
#pragma unroll
      for (int r = 0; r < 4; ++r) pk[r] = (bf16)(o[dt][qt][r] * iv);
      const int q = qt * 16 + l15;
      const int s16 = (dt * 2 + (g >> 1)) ^ (q & 15);     // 16 slots per 256B row
      *(bf16x4*)&bb[q * 128 + (s16 << 3) + ((g & 1) << 2)] = pk;
    }
  asm volatile("s_waitcnt lgkmcnt(0)" ::: "memory");
#pragma unroll
  for (int it = 0; it < 8; ++it) {
    const int c = lane + it * 64;
    const int q = c >> 4, s16 = c & 15;
    const bf16x8 vv = *(const bf16x8*)&bb[q * 128 + ((s16 ^ (q & 15)) << 3)];
    *(bf16x8*)(ob + (size_t)(b * S_ + q0 + q) * E_ + h * HD_ + s16 * 8) = vv;
  }
}

// ---------------- launcher ----------------
extern "C" void kernel_launch(void* const* d_in, const int* in_sizes, int n_in,
                              void* d_out, int out_size, void* d_ws, size_t ws_size,
                              hipStream_t stream) {
  const float* x   = (const float*)d_in[0];
  // d_in[1] = attn_mask: reference never applies it
  const float* wq  = (const float*)d_in[2];
  const float* bq  = (const float*)d_in[3];
  const float* wkv = (const float*)d_in[4];
  const float* bkv = (const float*)d_in[5];
  const float* wo  = (const float*)d_in[6];
  const float* wg  = (const float*)d_in[7];
  const float* wu  = (const float*)d_in[8];
  const float* wd  = (const float*)d_in[9];
  const float* n1  = (const float*)d_in[10];
  const float* n2  = (const float*)d_in[11];
  float* out = (float*)d_out;
  char* ws = (char*)d_ws;
  // Activations:
  bf16* y    = (bf16*)(ws);                   // 16 MiB [attn-out o; then y2]; later dn-part0
  bf16* qkvb = (bf16*)(ws + (16ull << 20));   // 24 MiB fused q|k|v; later dn-part1
  bf16* x1   = (bf16*)(ws + (40ull << 20));   // 16 MiB (bf16 residual)
  bf16* gh   = (bf16*)(ws + (56ull << 20));   // 64 MiB (h); first 4 MiB aliased as vT pre-gu
  bf16* vT   = gh;                            // 4 MiB, dead once gu writes gh
  bf16* o    = y;
  bf16* y2   = y;
  bf16* part0 = y;                            // down partials (y dead after gu)
  bf16* part1 = qkvb;                         // (qkvb dead after attn)
  // Tier A: bf16 weight mirrors, contiguous 116 MiB at +120
  bf16* wqkvb = (bf16*)(ws + (120ull << 20)); // 12 MiB: wq rows then wkv rows
  bf16* wob   = (bf16*)(ws + (132ull << 20)); // 8 MiB
  bf16* wgb   = (bf16*)(ws + (140ull << 20)); // 32 MiB
  bf16* wub   = (bf16*)(ws + (172ull << 20)); // 32 MiB
  bf16* wdb   = (bf16*)(ws + (204ull << 20)); // 32 MiB -> end 236 MiB
  const int M = B_ * S_;  // 4096
  const bool tierA = ws_size >= (236ull << 20);

  if (tierA)
    cvt6_k<<<2048, 256, 0, stream>>>(wq, wkv, wo, wg, wu, wd, wqkvb);

  rmsnorm_k<float><<<M, 256, 0, stream>>>(x, n1, y);
  if (tierA) {
    gemm_bt<0, true><<<dim3(QKS / 128, M / 128), 256, 0, stream>>>(
        y, wqkvb, bq, bkv, nullptr, qkvb, M, QKS, E_);
  } else {
    gemm_bt<0, false><<<dim3(E_ / 128, M / 128), 256, 0, stream>>>(
        y, wq, bq, nullptr, nullptr, qkvb, M, QKS, E_);
    gemm_bt<0, false><<<dim3(KVROW / 128, M / 128), 256, 0, stream>>>(
        y, wkv, bkv, nullptr, nullptr, qkvb + 2048, M, QKS, E_);
  }
  rope_k<<<(B_ * S_ * (H_ + KVH_) * 64) / 256, 256, 0, stream>>>(qkvb);
  vtrans_k<<<dim3(S_ / 64, KVH_, B_), 256, 0, stream>>>(qkvb, vT);
  attn_k<<<dim3(S_ / 128, H_, B_), 256, 0, stream>>>(qkvb, vT, o);
  if (tierA) {
    gemm_bt<1, true><<<dim3(E_ / 128, M / 128), 256, 0, stream>>>(
        o, wob, nullptr, nullptr, x, x1, M, E_, E_);
    rmsnorm_k<bf16><<<M, 256, 0, stream>>>(x1, n2, y2);
    gemm_gu<<<dim3(I_ / 128, M / 128), 256, 0, stream>>>(y2, wgb, wub, gh, M, I_, E_);
    gemm_dn<<<dim3(E_ / 256, M / 128, 2), 256, 0, stream>>>(gh, wdb, part0, part1, M, E_, I_);
    red_k<<<(M * E_) / (256 * 8), 256, 0, stream>>>(part0, part1, x1, out);
  } else {
    gemm_bt<1, false><<<dim3(E_ / 128, M / 128), 256, 0, stream>>>(
        o, wo, nullptr, nullptr, x, x1, M, E_, E_);
    rmsnorm_k<bf16><<<M, 256, 0, stream>>>(x1, n2, y2);
    gemm_bt<0, false><<<dim3(I_ / 128, M / 128), 256, 0, stream>>>(
        y2, wg, nullptr, nullptr, nullptr, gh, M, I_, E_);
    gemm_bt<2, false><<<dim3(I_ / 128, M / 128), 256, 0, stream>>>(
        y2, wu, nullptr, nullptr, gh, gh, M, I_, E_);
    gemm_bt<3, false><<<dim3(E_ / 128, M / 128), 256, 0, stream>>>(
        gh, wd, nullptr, nullptr, x1, out, M, E_, I_);
  }
}